// Round 7
// baseline (263.947 us; speedup 1.0000x reference)
//
#include <hip/hip_runtime.h>
#include <math.h>

#define DMODEL 1024
#define NQKV   3072
#define SEQ    1024
#define NH     16
#define DH     64
#define HS     (SEQ*DH)
constexpr float PI_F   = 3.14159265358979323846f;
constexpr float LOG2E  = 1.44269504088896f;

typedef _Float16 half8   __attribute__((ext_vector_type(8)));
typedef _Float16 half4   __attribute__((ext_vector_type(4)));
typedef float    floatx4 __attribute__((ext_vector_type(4)));

// async global->LDS, 16B per lane; LDS dest is wave-uniform base + lane*16
__device__ __forceinline__ void gload_lds16(const _Float16* g, _Float16* l) {
    __builtin_amdgcn_global_load_lds(
        (const __attribute__((address_space(1))) unsigned int*)g,
        (__attribute__((address_space(3)))       unsigned int*)l,
        16, 0, 0);
}

// ---------------------------------------------------------------------------
// flat fp32 -> f16 convert
// ---------------------------------------------------------------------------
__global__ __launch_bounds__(256) void cvt_f16(
    const float* __restrict__ in, _Float16* __restrict__ out, int n)
{
    int i = (blockIdx.x*256 + threadIdx.x)*8;
    if (i >= n) return;
    float4 a = *(const float4*)(in + i);
    float4 b = *(const float4*)(in + i + 4);
    half8 h;
    h[0]=(_Float16)a.x; h[1]=(_Float16)a.y; h[2]=(_Float16)a.z; h[3]=(_Float16)a.w;
    h[4]=(_Float16)b.x; h[5]=(_Float16)b.y; h[6]=(_Float16)b.z; h[7]=(_Float16)b.w;
    *(half8*)(out + i) = h;
}

// ---------------------------------------------------------------------------
// transpose + convert: in [R][C] fp32 -> out [C][R] f16   (32x32 tiles)
// ---------------------------------------------------------------------------
__global__ __launch_bounds__(256) void tr_cvt(
    const float* __restrict__ in, _Float16* __restrict__ out, int R, int C)
{
    __shared__ float T[32][33];
    const int bx = blockIdx.x, by = blockIdx.y;
    const int tx = threadIdx.x & 31, ty = threadIdx.x >> 5;
#pragma unroll
    for (int i = 0; i < 4; ++i)
        T[ty + i*8][tx] = in[(size_t)(by*32 + ty + i*8)*C + bx*32 + tx];
    __syncthreads();
#pragma unroll
    for (int i = 0; i < 4; ++i)
        out[(size_t)(bx*32 + ty + i*8)*R + by*32 + tx] = (_Float16)T[tx][ty + i*8];
}

// ---------------------------------------------------------------------------
// gemm1: R2 measured-best (69.5us). 256x256 tile, BK=64 as 2 k-halves,
// 8 waves (2Mx4N, 128x64/wave). Counted-vmcnt 2-super-phase schedule:
// stage order/tile A-k0'(2) B-k0'(2) A-k1'(2) B-k1'(2); SP gates vmcnt(6)
// (last tile 4/0); one barrier per SP; split lgkmcnt(4)/(0) MFMA halves.
// LDS [buf][khalf][256][32]; read swizzle chunk=quad^((l>>1)&3); staging
// source inverse-swizzled (0 bank conflicts, measured). Grid 12x32=384.
// ---------------------------------------------------------------------------
__global__ __launch_bounds__(512) void gemm1_f16(
    const _Float16* __restrict__ A, const _Float16* __restrict__ Bt,
    _Float16* __restrict__ C, int M, int N, int K)
{
    __shared__ _Float16 As[2][2][8192] __attribute__((aligned(16)));
    __shared__ _Float16 Bs[2][2][8192] __attribute__((aligned(16)));

    const int tid  = threadIdx.x;
    const int w    = tid >> 6, lane = tid & 63, quad = lane >> 4, l = lane & 15;
    const int wm   = (w >> 2)*128, wn = (w & 3)*64;

    int bid = blockIdx.y*gridDim.x + blockIdx.x;
    const int per = (gridDim.x*gridDim.y) >> 3;
    bid = (bid & 7)*per + (bid >> 3);
    const int bx = bid % gridDim.x, by = bid / gridDim.x;
    const int m0 = by*256, n0 = bx*256;

    const int rs   = tid >> 2;
    const int csrc = (tid & 3) ^ ((tid >> 3) & 3);
    const _Float16* ga = A  + (size_t)(m0 + rs)*K + csrc*8;
    const _Float16* gb = Bt + (size_t)(n0 + rs)*K + csrc*8;
    const int swz8 = (quad ^ ((l >> 1) & 3))*8;

    floatx4 acc[8][4];
#pragma unroll
    for (int i = 0; i < 8; ++i)
#pragma unroll
        for (int j = 0; j < 4; ++j)
#pragma unroll
            for (int r = 0; r < 4; ++r) acc[i][j][r] = 0.f;

    // prologue: tile 0, order A-k0(2), B-k0(2), A-k1(2), B-k1(2)
    gload_lds16(ga,                      &As[0][0][w*512]);
    gload_lds16(ga + (size_t)128*K,      &As[0][0][4096 + w*512]);
    gload_lds16(gb,                      &Bs[0][0][w*512]);
    gload_lds16(gb + (size_t)128*K,      &Bs[0][0][4096 + w*512]);
    gload_lds16(ga + 32,                 &As[0][1][w*512]);
    gload_lds16(ga + 32 + (size_t)128*K, &As[0][1][4096 + w*512]);
    gload_lds16(gb + 32,                 &Bs[0][1][w*512]);
    gload_lds16(gb + 32 + (size_t)128*K, &Bs[0][1][4096 + w*512]);

    const int KT = K / 64;
    for (int kt = 0; kt < KT; ++kt) {
        const int cur = kt & 1, nxt = cur ^ 1;
        const bool pf = (kt + 1 < KT);
        const size_t ko = (size_t)(kt + 1)*64;
        half8 af[8], bf[4];

        // ================= SP0 : k-half 0 =================
        if (pf) {
            gload_lds16(ga + ko,                 &As[nxt][0][w*512]);
            gload_lds16(ga + ko + (size_t)128*K, &As[nxt][0][4096 + w*512]);
        }
        if (pf) { asm volatile("s_waitcnt vmcnt(6)" ::: "memory"); }
        else    { asm volatile("s_waitcnt vmcnt(4)" ::: "memory"); }
        __builtin_amdgcn_s_barrier();
        __builtin_amdgcn_sched_barrier(0);
#pragma unroll
        for (int mt = 0; mt < 4; ++mt)
            af[mt] = *(half8*)&As[cur][0][(wm + mt*16 + l)*32 + swz8];
#pragma unroll
        for (int nt = 0; nt < 4; ++nt)
            bf[nt] = *(half8*)&Bs[cur][0][(wn + nt*16 + l)*32 + swz8];
        __builtin_amdgcn_sched_barrier(0);
#pragma unroll
        for (int mt = 4; mt < 8; ++mt)
            af[mt] = *(half8*)&As[cur][0][(wm + mt*16 + l)*32 + swz8];
        if (pf) {
            gload_lds16(gb + ko,                 &Bs[nxt][0][w*512]);
            gload_lds16(gb + ko + (size_t)128*K, &Bs[nxt][0][4096 + w*512]);
        }
        asm volatile("s_waitcnt lgkmcnt(4)" ::: "memory");
        __builtin_amdgcn_sched_barrier(0);
        __builtin_amdgcn_s_setprio(1);
#pragma unroll
        for (int mt = 0; mt < 4; ++mt)
#pragma unroll
            for (int nt = 0; nt < 4; ++nt)
                acc[mt][nt] = __builtin_amdgcn_mfma_f32_16x16x32_f16(af[mt], bf[nt], acc[mt][nt], 0, 0, 0);
        __builtin_amdgcn_s_setprio(0);
        asm volatile("s_waitcnt lgkmcnt(0)" ::: "memory");
        __builtin_amdgcn_sched_barrier(0);
        __builtin_amdgcn_s_setprio(1);
#pragma unroll
        for (int mt = 4; mt < 8; ++mt)
#pragma unroll
            for (int nt = 0; nt < 4; ++nt)
                acc[mt][nt] = __builtin_amdgcn_mfma_f32_16x16x32_f16(af[mt], bf[nt], acc[mt][nt], 0, 0, 0);
        __builtin_amdgcn_s_setprio(0);

        // ================= SP1 : k-half 1 =================
        if (pf) {
            gload_lds16(ga + ko + 32,                 &As[nxt][1][w*512]);
            gload_lds16(ga + ko + 32 + (size_t)128*K, &As[nxt][1][4096 + w*512]);
        }
        if (pf) { asm volatile("s_waitcnt vmcnt(6)" ::: "memory"); }
        else    { asm volatile("s_waitcnt vmcnt(0)" ::: "memory"); }
        __builtin_amdgcn_s_barrier();
        __builtin_amdgcn_sched_barrier(0);
#pragma unroll
        for (int mt = 0; mt < 4; ++mt)
            af[mt] = *(half8*)&As[cur][1][(wm + mt*16 + l)*32 + swz8];
#pragma unroll
        for (int nt = 0; nt < 4; ++nt)
            bf[nt] = *(half8*)&Bs[cur][1][(wn + nt*16 + l)*32 + swz8];
        __builtin_amdgcn_sched_barrier(0);
#pragma unroll
        for (int mt = 4; mt < 8; ++mt)
            af[mt] = *(half8*)&As[cur][1][(wm + mt*16 + l)*32 + swz8];
        if (pf) {
            gload_lds16(gb + ko + 32,                 &Bs[nxt][1][w*512]);
            gload_lds16(gb + ko + 32 + (size_t)128*K, &Bs[nxt][1][4096 + w*512]);
        }
        asm volatile("s_waitcnt lgkmcnt(4)" ::: "memory");
        __builtin_amdgcn_sched_barrier(0);
        __builtin_amdgcn_s_setprio(1);
#pragma unroll
        for (int mt = 0; mt < 4; ++mt)
#pragma unroll
            for (int nt = 0; nt < 4; ++nt)
                acc[mt][nt] = __builtin_amdgcn_mfma_f32_16x16x32_f16(af[mt], bf[nt], acc[mt][nt], 0, 0, 0);
        __builtin_amdgcn_s_setprio(0);
        asm volatile("s_waitcnt lgkmcnt(0)" ::: "memory");
        __builtin_amdgcn_sched_barrier(0);
        __builtin_amdgcn_s_setprio(1);
#pragma unroll
        for (int mt = 4; mt < 8; ++mt)
#pragma unroll
            for (int nt = 0; nt < 4; ++nt)
                acc[mt][nt] = __builtin_amdgcn_mfma_f32_16x16x32_f16(af[mt], bf[nt], acc[mt][nt], 0, 0, 0);
        __builtin_amdgcn_s_setprio(0);
    }

#pragma unroll
    for (int mt = 0; mt < 8; ++mt)
#pragma unroll
        for (int r = 0; r < 4; ++r) {
            size_t row = m0 + wm + mt*16 + quad*4 + r;
#pragma unroll
            for (int nt = 0; nt < 4; ++nt)
                C[row*N + n0 + wn + nt*16 + l] = (_Float16)acc[mt][nt][r];
        }
}

// ---------------------------------------------------------------------------
// gemm2: R6 core (128x256, tail-free 256 blocks), fp32 output + bias.
// ---------------------------------------------------------------------------
__global__ __launch_bounds__(512) void gemm2_f16(
    const _Float16* __restrict__ A, const _Float16* __restrict__ Bt,
    const float* __restrict__ bias, float* __restrict__ C, int M, int N, int K)
{
    __shared__ _Float16 As[2][2][4096] __attribute__((aligned(16)));
    __shared__ _Float16 Bs[2][2][8192] __attribute__((aligned(16)));

    const int tid  = threadIdx.x;
    const int w    = tid >> 6, lane = tid & 63, quad = lane >> 4, l = lane & 15;
    const int wm   = (w >> 2)*64, wn = (w & 3)*64;

    int bid = blockIdx.y*gridDim.x + blockIdx.x;
    const int per = (gridDim.x*gridDim.y) >> 3;
    bid = (bid & 7)*per + (bid >> 3);
    const int bx = bid % gridDim.x, by = bid / gridDim.x;
    const int m0 = by*128, n0 = bx*256;

    const int rs   = tid >> 2;
    const int csrc = (tid & 3) ^ ((tid >> 3) & 3);
    const _Float16* ga = A  + (size_t)(m0 + rs)*K + csrc*8;
    const _Float16* gb = Bt + (size_t)(n0 + rs)*K + csrc*8;
    const int swz8 = (quad ^ ((l >> 1) & 3))*8;

    floatx4 acc[4][4];
#pragma unroll
    for (int i = 0; i < 4; ++i)
#pragma unroll
        for (int j = 0; j < 4; ++j)
#pragma unroll
            for (int r = 0; r < 4; ++r) acc[i][j][r] = 0.f;

    gload_lds16(ga,                        &As[0][0][w*512]);
    gload_lds16(gb,                        &Bs[0][0][w*512]);
    gload_lds16(gb + (size_t)128*K,        &Bs[0][0][4096 + w*512]);
    gload_lds16(ga + 32,                   &As[0][1][w*512]);
    gload_lds16(gb + 32,                   &Bs[0][1][w*512]);
    gload_lds16(gb + 32 + (size_t)128*K,   &Bs[0][1][4096 + w*512]);

    const int KT = K / 64;
    for (int kt = 0; kt < KT; ++kt) {
        const int cur = kt & 1, nxt = cur ^ 1;
        const bool pf = (kt + 1 < KT);
        const size_t ko = (size_t)(kt + 1)*64;
        half8 af[4], bf[4];

        // ================= SP0 =================
        if (pf) gload_lds16(ga + ko, &As[nxt][0][w*512]);
        if (pf) { asm volatile("s_waitcnt vmcnt(4)" ::: "memory"); }
        else    { asm volatile("s_waitcnt vmcnt(3)" ::: "memory"); }
        __builtin_amdgcn_s_barrier();
        __builtin_amdgcn_sched_barrier(0);
#pragma unroll
        for (int mt = 0; mt < 4; ++mt)
            af[mt] = *(half8*)&As[cur][0][(wm + mt*16 + l)*32 + swz8];
#pragma unroll
        for (int nt = 0; nt < 4; ++nt)
            bf[nt] = *(half8*)&Bs[cur][0][(wn + nt*16 + l)*32 + swz8];
        if (pf) {
            gload_lds16(gb + ko,                 &Bs[nxt][0][w*512]);
            gload_lds16(gb + ko + (size_t)128*K, &Bs[nxt][0][4096 + w*512]);
        }
        asm volatile("s_waitcnt lgkmcnt(0)" ::: "memory");
        __builtin_amdgcn_sched_barrier(0);
        __builtin_amdgcn_s_setprio(1);
#pragma unroll
        for (int mt = 0; mt < 4; ++mt)
#pragma unroll
            for (int nt = 0; nt < 4; ++nt)
                acc[mt][nt] = __builtin_amdgcn_mfma_f32_16x16x32_f16(af[mt], bf[nt], acc[mt][nt], 0, 0, 0);
        __builtin_amdgcn_s_setprio(0);

        // ================= SP1 =================
        if (pf) gload_lds16(ga + ko + 32, &As[nxt][1][w*512]);
        if (pf) { asm volatile("s_waitcnt vmcnt(4)" ::: "memory"); }
        else    { asm volatile("s_waitcnt vmcnt(0)" ::: "memory"); }
        __builtin_amdgcn_s_barrier();
        __builtin_amdgcn_sched_barrier(0);
#pragma unroll
        for (int mt = 0; mt < 4; ++mt)
            af[mt] = *(half8*)&As[cur][1][(wm + mt*16 + l)*32 + swz8];
#pragma unroll
        for (int nt = 0; nt < 4; ++nt)
            bf[nt] = *(half8*)&Bs[cur][1][(wn + nt*16 + l)*32 + swz8];
        if (pf) {
            gload_lds16(gb + ko + 32,                 &Bs[nxt][1][w*512]);
            gload_lds16(gb + ko + 32 + (size_t)128*K, &Bs[nxt][1][4096 + w*512]);
        }
        asm volatile("s_waitcnt lgkmcnt(0)" ::: "memory");
        __builtin_amdgcn_sched_barrier(0);
        __builtin_amdgcn_s_setprio(1);
#pragma unroll
        for (int mt = 0; mt < 4; ++mt)
#pragma unroll
            for (int nt = 0; nt < 4; ++nt)
                acc[mt][nt] = __builtin_amdgcn_mfma_f32_16x16x32_f16(af[mt], bf[nt], acc[mt][nt], 0, 0, 0);
        __builtin_amdgcn_s_setprio(0);
    }

#pragma unroll
    for (int mt = 0; mt < 4; ++mt)
#pragma unroll
        for (int r = 0; r < 4; ++r) {
            size_t row = m0 + wm + mt*16 + quad*4 + r;
#pragma unroll
            for (int nt = 0; nt < 4; ++nt) {
                int col = n0 + wn + nt*16 + l;
                C[row*N + col] = acc[mt][nt][r] + bias[col];
            }
        }
}

// ---------------------------------------------------------------------------
// rope + scatter. q pre-scaled by (1/8)*log2e so attention exp is bare exp2.
// ---------------------------------------------------------------------------
__global__ __launch_bounds__(256) void rope_scatter(
    const _Float16* __restrict__ qkv,
    _Float16* __restrict__ qw, _Float16* __restrict__ kw,
    _Float16* __restrict__ vt)
{
    const int sc = blockIdx.x;
    const int bh = blockIdx.y;
    const int bt = bh >> 4, head = bh & 15;
    const int s0 = sc*64;
    const int tid = threadIdx.x;
    const int d0 = (tid & 7)*8;

    __shared__ _Float16 T[64][80];

#pragma unroll
    for (int half = 0; half < 2; ++half) {
        const int r = (tid >> 3) + half*32;
        const int s = s0 + r;
        const _Float16* src = qkv + (size_t)(bt*SEQ + s)*NQKV + head*DH + d0;
        half8 hq = *(const half8*)(src);
        half8 hk = *(const half8*)(src + DMODEL);
        half8 hv = *(const half8*)(src + 2*DMODEL);
        float fq[8], fk[8];
#pragma unroll
        for (int j = 0; j < 8; ++j) { fq[j] = (float)hq[j]; fk[j] = (float)hk[j]; }
        const int hp = s >> 5, wp = s & 31;
        const float ph = -1.0f + hp*(2.0f/31.0f);
        const float pw = -1.0f + wp*(2.0f/31.0f);
#pragma unroll
        for (int p = 0; p < 4; ++p) {
            int pg = (d0 >> 1) + p;
            float pos = (pg < 16) ? ph : pw;
            int   gi  = (pg < 16) ? pg : (pg - 16);
            float th  = pos * ((1.0f + gi*(127.0f/15.0f)) * PI_F);
            float sn, cs;
            sincosf(th, &sn, &cs);
            float q1 = fq[2*p], q2 = fq[2*p+1];
            fq[2*p]   = q1*cs - q2*sn;
            fq[2*p+1] = q2*cs + q1*sn;
            float k1 = fk[2*p], k2 = fk[2*p+1];
            fk[2*p]   = k1*cs - k2*sn;
            fk[2*p+1] = k2*cs + k1*sn;
        }
        half8 oq, ok;
        const float qsc = 0.125f * LOG2E;
#pragma unroll
        for (int j = 0; j < 8; ++j) {
            oq[j] = (_Float16)(fq[j]*qsc);
            ok[j] = (_Float16)fk[j];
        }
        *(half8*)(qw + (size_t)bh*HS + (size_t)s*DH + d0) = oq;
        *(half8*)(kw + (size_t)bh*HS + (size_t)s*DH + d0) = ok;
#pragma unroll
        for (int j = 0; j < 8; ++j) T[d0 + j][r] = hv[j];
    }
    __syncthreads();
    const int d = tid >> 2, so = (tid & 3)*16;
    half8 v0 = *(half8*)&T[d][so];
    half8 v1 = *(half8*)&T[d][so + 8];
    _Float16* dst = vt + (size_t)bh*HS + (size_t)d*SEQ + s0 + so;
    *(half8*)dst       = v0;
    *(half8*)(dst + 8) = v1;
}

// ---------------------------------------------------------------------------
// Flash attention v5: BQ=256 per block, 4 waves x 64 queries (4 q-tiles).
// K/V A-frags and V B-frags read ONCE per chunk, reused across 4 q-tiles
// -> per-chunk LDS reads 24 b128 per 64 MFMA (was 20 per 32). 512 blocks
// (=2/CU, zero tail), K/V HBM staging traffic halved vs BQ=128.
// QK->exp->P-store fused per (kg,qt) so only one floatx4 S is live.
// ---------------------------------------------------------------------------
#define BC  64
#define LDH 68     // padded row stride (halfwords): rows shift 2 banks; <=2-way on frags

__global__ __launch_bounds__(256) void attn_mfma(
    const _Float16* __restrict__ qw, const _Float16* __restrict__ kw,
    const _Float16* __restrict__ vt, _Float16* __restrict__ om)
{
    const int qc = blockIdx.x;    // 0..3  (256-query chunk)
    const int bh = blockIdx.y;    // 0..127
    const int tid  = threadIdx.x;
    const int w    = tid >> 6;
    const int lane = tid & 63;
    const int quad = lane >> 4;
    const int l    = lane & 15;

    __shared__ _Float16 Ks[2][BC][LDH];
    __shared__ _Float16 Vs[2][DH][LDH];
    __shared__ _Float16 Ps[4][64][LDH];
    __shared__ float    Ls[4][64];

    const _Float16* qp = qw + (size_t)bh*HS + (size_t)(qc*256 + w*64)*DH;
    const _Float16* kp = kw + (size_t)bh*HS;
    const _Float16* vp = vt + (size_t)bh*HS;   // [d][1024]

    // Q B-frags for this wave's 4 q-tiles (held all loop)
    half8 qf[4][2];
#pragma unroll
    for (int qt = 0; qt < 4; ++qt) {
        qf[qt][0] = *(const half8*)(qp + (size_t)(qt*16 + l)*DH + quad*8);
        qf[qt][1] = *(const half8*)(qp + (size_t)(qt*16 + l)*DH + quad*8 + 32);
    }

    const int rs = tid >> 3;           // 0..31
    const int cs = (tid & 7)*8;        // 0..56

    half8 kr0 = *(const half8*)(kp + (size_t)rs*DH + cs);
    half8 kr1 = *(const half8*)(kp + (size_t)(rs+32)*DH + cs);
    half8 vr0 = *(const half8*)(vp + (size_t)rs*SEQ + cs);
    half8 vr1 = *(const half8*)(vp + (size_t)(rs+32)*SEQ + cs);
    *(half8*)&Ks[0][rs][cs]    = kr0;
    *(half8*)&Ks[0][rs+32][cs] = kr1;
    *(half8*)&Vs[0][rs][cs]    = vr0;
    *(half8*)&Vs[0][rs+32][cs] = vr1;

    floatx4 Of[4][4];
#pragma unroll
    for (int qt = 0; qt < 4; ++qt)
#pragma unroll
        for (int dt = 0; dt < 4; ++dt)
#pragma unroll
            for (int r = 0; r < 4; ++r) Of[qt][dt][r] = 0.f;
    float lsum[4] = {0.f, 0.f, 0.f, 0.f};

    __syncthreads();

    for (int kc = 0; kc < SEQ/BC; ++kc) {
        const int cur = kc & 1;
        if (kc < SEQ/BC - 1) {
            const _Float16* kn = kp + (size_t)(kc+1)*BC*DH;
            const _Float16* vn = vp + (size_t)(kc+1)*BC;
            kr0 = *(const half8*)(kn + (size_t)rs*DH + cs);
            kr1 = *(const half8*)(kn + (size_t)(rs+32)*DH + cs);
            vr0 = *(const half8*)(vn + (size_t)rs*SEQ + cs);
            vr1 = *(const half8*)(vn + (size_t)(rs+32)*SEQ + cs);
        }

        // S^T = K.Q^T, fused exp2 + P store per (kg, qt); one S tile live
#pragma unroll
        for (int kg = 0; kg < 4; ++kg) {
            half8 af0 = *(half8*)&Ks[cur][kg*16 + l][quad*8];
            half8 af1 = *(half8*)&Ks[cur][kg*16 + l][quad*8 + 32];
#pragma unroll
            for (int qt = 0; qt < 4; ++qt) {
                floatx4 a;
#pragma unroll
                for (int r = 0; r < 4; ++r) a[r] = 0.f;
                a = __builtin_amdgcn_mfma_f32_16x16x32_f16(af0, qf[qt][0], a, 0, 0, 0);
                a = __builtin_amdgcn_mfma_f32_16x16x32_f16(af1, qf[qt][1], a, 0, 0, 0);
                half4 p4;
#pragma unroll
                for (int r = 0; r < 4; ++r) {
                    float p = __builtin_amdgcn_exp2f(a[r]);
                    lsum[qt] += p;
                    p4[r] = (_Float16)p;
                }
                *(half4*)&Ps[w][qt*16 + l][kg*16 + quad*4] = p4;
            }
        }
        // PV: A = P b128 frags (wave-private), B = V^T (read once, 4x reuse)
        half8 pa[4][2];
#pragma unroll
        for (int qt = 0; qt < 4; ++qt) {
            pa[qt][0] = *(half8*)&Ps[w][qt*16 + l][quad*8];
            pa[qt][1] = *(half8*)&Ps[w][qt*16 + l][quad*8 + 32];
        }
#pragma unroll
        for (int dt = 0; dt < 4; ++dt) {
            half8 vb0 = *(half8*)&Vs[cur][dt*16 + l][quad*8];
            half8 vb1 = *(half8*)&Vs[cur][dt*16 + l][quad*8 + 32];
#pragma unroll
            for (int qt = 0; qt < 4; ++qt) {
                Of[qt][dt] = __builtin_amdgcn_mfma_f32_16x16x32_f16(pa[qt][0], vb0, Of[qt][dt], 0, 0, 0);
                Of[qt][dt] = __builtin_amdgcn_mfma_f32_16x16x32_f16(pa[qt][1], vb1, Of[qt][dt], 0, 0, 0);
            }
        }

        if (kc < SEQ/BC - 1) {
            *(half8*)&Ks[1-cur][rs][cs]    = kr0;
            *(half8*)&Ks[1-cur][rs+32][cs] = kr1;
            *(half8*)&Vs[1-cur][rs][cs]    = vr0;
            *(half8*)&Vs[1-cur][rs+32][cs] = vr1;
        }
        __syncthreads();
    }

    // final l: reduce across quads, redistribute via per-wave LDS
#pragma unroll
    for (int qt = 0; qt < 4; ++qt) {
        lsum[qt] += __shfl_xor(lsum[qt], 16);
        lsum[qt] += __shfl_xor(lsum[qt], 32);
        if (quad == 0) Ls[w][qt*16 + l] = lsum[qt];
    }
    const int bt = bh >> 4, head = bh & 15;
    _Float16* opf = om + (size_t)(bt*SEQ + qc*256 + w*64)*DMODEL + head*DH;
#pragma unroll
    for (int qt = 0; qt < 4; ++qt) {
        float inv[4];
#pragma unroll
        for (int r = 0; r < 4; ++r) inv[r] = 1.0f / Ls[w][qt*16 + quad*4 + r];
#pragma unroll
        for (int dt = 0; dt < 4; ++dt)
#pragma unroll
            for (int r = 0; r < 4; ++r)
                opf[(size_t)(qt*16 + quad*4 + r)*DMODEL + dt*16 + l] =
                    (_Float16)(Of[qt][dt][r]*inv[r]);
    }
}

// ---------------------------------------------------------------------------
extern "C" void kernel_launch(void* const* d_in, const int* in_sizes, int n_in,
                              void* d_out, int out_size, void* d_ws, size_t ws_size,
                              hipStream_t stream)
{
    const float* x    = (const float*)d_in[0];
    const float* Wqkv = (const float*)d_in[1];
    const float* Wout = (const float*)d_in[2];
    const float* bout = (const float*)d_in[3];
    float* out = (float*)d_out;

    _Float16* ws   = (_Float16*)d_ws;
    _Float16* Xh   = ws;                  // 8388608
    _Float16* Wqkt = ws + 8388608;        // 3145728  [3072][1024]
    _Float16* Wot  = ws + 11534336;       // 1048576  [1024][1024]
    _Float16* qkvt = ws + 12582912;       // 25165824 [8192][3072]
    _Float16* qw   = ws + 37748736;       // 8388608
    _Float16* kw   = ws + 46137344;       // 8388608
    _Float16* vt   = ws + 54525952;       // 8388608  (end: 120 MiB)
    _Float16* om   = qkvt;                // alias: reused after rope_scatter

    hipLaunchKernelGGL(cvt_f16, dim3(4096), dim3(256), 0, stream,
                       x, Xh, 8388608);
    hipLaunchKernelGGL(tr_cvt, dim3(96, 32), dim3(256), 0, stream,
                       Wqkv, Wqkt, 1024, 3072);
    hipLaunchKernelGGL(tr_cvt, dim3(32, 32), dim3(256), 0, stream,
                       Wout, Wot, 1024, 1024);
    hipLaunchKernelGGL(gemm1_f16, dim3(12, 32), dim3(512), 0, stream,
                       Xh, Wqkt, qkvt, 8192, NQKV, DMODEL);
    hipLaunchKernelGGL(rope_scatter, dim3(16, 128), dim3(256), 0, stream,
                       qkvt, qw, kw, vt);
    hipLaunchKernelGGL(attn_mfma, dim3(4, 128), dim3(256), 0, stream,
                       qw, kw, vt, om);
    hipLaunchKernelGGL(gemm2_f16, dim3(4, 64), dim3(512), 0, stream,
                       om, Wot, bout, out, 8192, DMODEL, DMODEL);
}

// Round 8
// 247.660 us; speedup vs baseline: 1.0658x; 1.0658x over previous
//
#include <hip/hip_runtime.h>
#include <math.h>

#define DMODEL 1024
#define NQKV   3072
#define SEQ    1024
#define NH     16
#define DH     64
#define HS     (SEQ*DH)
constexpr float PI_F   = 3.14159265358979323846f;
constexpr float LOG2E  = 1.44269504088896f;

typedef _Float16 half8   __attribute__((ext_vector_type(8)));
typedef _Float16 half4   __attribute__((ext_vector_type(4)));
typedef float    floatx4 __attribute__((ext_vector_type(4)));

// async global->LDS, 16B per lane; LDS dest is wave-uniform base + lane*16
__device__ __forceinline__ void gload_lds16(const _Float16* g, _Float16* l) {
    __builtin_amdgcn_global_load_lds(
        (const __attribute__((address_space(1))) unsigned int*)g,
        (__attribute__((address_space(3)))       unsigned int*)l,
        16, 0, 0);
}

// ---------------------------------------------------------------------------
// flat fp32 -> f16 convert
// ---------------------------------------------------------------------------
__global__ __launch_bounds__(256) void cvt_f16(
    const float* __restrict__ in, _Float16* __restrict__ out, int n)
{
    int i = (blockIdx.x*256 + threadIdx.x)*8;
    if (i >= n) return;
    float4 a = *(const float4*)(in + i);
    float4 b = *(const float4*)(in + i + 4);
    half8 h;
    h[0]=(_Float16)a.x; h[1]=(_Float16)a.y; h[2]=(_Float16)a.z; h[3]=(_Float16)a.w;
    h[4]=(_Float16)b.x; h[5]=(_Float16)b.y; h[6]=(_Float16)b.z; h[7]=(_Float16)b.w;
    *(half8*)(out + i) = h;
}

// ---------------------------------------------------------------------------
// transpose + convert: in [R][C] fp32 -> out [C][R] f16   (32x32 tiles)
// ---------------------------------------------------------------------------
__global__ __launch_bounds__(256) void tr_cvt(
    const float* __restrict__ in, _Float16* __restrict__ out, int R, int C)
{
    __shared__ float T[32][33];
    const int bx = blockIdx.x, by = blockIdx.y;
    const int tx = threadIdx.x & 31, ty = threadIdx.x >> 5;
#pragma unroll
    for (int i = 0; i < 4; ++i)
        T[ty + i*8][tx] = in[(size_t)(by*32 + ty + i*8)*C + bx*32 + tx];
    __syncthreads();
#pragma unroll
    for (int i = 0; i < 4; ++i)
        out[(size_t)(bx*32 + ty + i*8)*R + by*32 + tx] = (_Float16)T[tx][ty + i*8];
}

// ---------------------------------------------------------------------------
// gemm1: R2 measured-best (69.5us). 256x256 tile, BK=64 as 2 k-halves,
// 8 waves (2Mx4N, 128x64/wave). Counted-vmcnt 2-super-phase schedule.
// Grid 12x32=384.
// ---------------------------------------------------------------------------
__global__ __launch_bounds__(512) void gemm1_f16(
    const _Float16* __restrict__ A, const _Float16* __restrict__ Bt,
    _Float16* __restrict__ C, int M, int N, int K)
{
    __shared__ _Float16 As[2][2][8192] __attribute__((aligned(16)));
    __shared__ _Float16 Bs[2][2][8192] __attribute__((aligned(16)));

    const int tid  = threadIdx.x;
    const int w    = tid >> 6, lane = tid & 63, quad = lane >> 4, l = lane & 15;
    const int wm   = (w >> 2)*128, wn = (w & 3)*64;

    int bid = blockIdx.y*gridDim.x + blockIdx.x;
    const int per = (gridDim.x*gridDim.y) >> 3;
    bid = (bid & 7)*per + (bid >> 3);
    const int bx = bid % gridDim.x, by = bid / gridDim.x;
    const int m0 = by*256, n0 = bx*256;

    const int rs   = tid >> 2;
    const int csrc = (tid & 3) ^ ((tid >> 3) & 3);
    const _Float16* ga = A  + (size_t)(m0 + rs)*K + csrc*8;
    const _Float16* gb = Bt + (size_t)(n0 + rs)*K + csrc*8;
    const int swz8 = (quad ^ ((l >> 1) & 3))*8;

    floatx4 acc[8][4];
#pragma unroll
    for (int i = 0; i < 8; ++i)
#pragma unroll
        for (int j = 0; j < 4; ++j)
#pragma unroll
            for (int r = 0; r < 4; ++r) acc[i][j][r] = 0.f;

    // prologue: tile 0, order A-k0(2), B-k0(2), A-k1(2), B-k1(2)
    gload_lds16(ga,                      &As[0][0][w*512]);
    gload_lds16(ga + (size_t)128*K,      &As[0][0][4096 + w*512]);
    gload_lds16(gb,                      &Bs[0][0][w*512]);
    gload_lds16(gb + (size_t)128*K,      &Bs[0][0][4096 + w*512]);
    gload_lds16(ga + 32,                 &As[0][1][w*512]);
    gload_lds16(ga + 32 + (size_t)128*K, &As[0][1][4096 + w*512]);
    gload_lds16(gb + 32,                 &Bs[0][1][w*512]);
    gload_lds16(gb + 32 + (size_t)128*K, &Bs[0][1][4096 + w*512]);

    const int KT = K / 64;
    for (int kt = 0; kt < KT; ++kt) {
        const int cur = kt & 1, nxt = cur ^ 1;
        const bool pf = (kt + 1 < KT);
        const size_t ko = (size_t)(kt + 1)*64;
        half8 af[8], bf[4];

        // ================= SP0 : k-half 0 =================
        if (pf) {
            gload_lds16(ga + ko,                 &As[nxt][0][w*512]);
            gload_lds16(ga + ko + (size_t)128*K, &As[nxt][0][4096 + w*512]);
        }
        if (pf) { asm volatile("s_waitcnt vmcnt(6)" ::: "memory"); }
        else    { asm volatile("s_waitcnt vmcnt(4)" ::: "memory"); }
        __builtin_amdgcn_s_barrier();
        __builtin_amdgcn_sched_barrier(0);
#pragma unroll
        for (int mt = 0; mt < 4; ++mt)
            af[mt] = *(half8*)&As[cur][0][(wm + mt*16 + l)*32 + swz8];
#pragma unroll
        for (int nt = 0; nt < 4; ++nt)
            bf[nt] = *(half8*)&Bs[cur][0][(wn + nt*16 + l)*32 + swz8];
        __builtin_amdgcn_sched_barrier(0);
#pragma unroll
        for (int mt = 4; mt < 8; ++mt)
            af[mt] = *(half8*)&As[cur][0][(wm + mt*16 + l)*32 + swz8];
        if (pf) {
            gload_lds16(gb + ko,                 &Bs[nxt][0][w*512]);
            gload_lds16(gb + ko + (size_t)128*K, &Bs[nxt][0][4096 + w*512]);
        }
        asm volatile("s_waitcnt lgkmcnt(4)" ::: "memory");
        __builtin_amdgcn_sched_barrier(0);
        __builtin_amdgcn_s_setprio(1);
#pragma unroll
        for (int mt = 0; mt < 4; ++mt)
#pragma unroll
            for (int nt = 0; nt < 4; ++nt)
                acc[mt][nt] = __builtin_amdgcn_mfma_f32_16x16x32_f16(af[mt], bf[nt], acc[mt][nt], 0, 0, 0);
        __builtin_amdgcn_s_setprio(0);
        asm volatile("s_waitcnt lgkmcnt(0)" ::: "memory");
        __builtin_amdgcn_sched_barrier(0);
        __builtin_amdgcn_s_setprio(1);
#pragma unroll
        for (int mt = 4; mt < 8; ++mt)
#pragma unroll
            for (int nt = 0; nt < 4; ++nt)
                acc[mt][nt] = __builtin_amdgcn_mfma_f32_16x16x32_f16(af[mt], bf[nt], acc[mt][nt], 0, 0, 0);
        __builtin_amdgcn_s_setprio(0);

        // ================= SP1 : k-half 1 =================
        if (pf) {
            gload_lds16(ga + ko + 32,                 &As[nxt][1][w*512]);
            gload_lds16(ga + ko + 32 + (size_t)128*K, &As[nxt][1][4096 + w*512]);
        }
        if (pf) { asm volatile("s_waitcnt vmcnt(6)" ::: "memory"); }
        else    { asm volatile("s_waitcnt vmcnt(0)" ::: "memory"); }
        __builtin_amdgcn_s_barrier();
        __builtin_amdgcn_sched_barrier(0);
#pragma unroll
        for (int mt = 0; mt < 4; ++mt)
            af[mt] = *(half8*)&As[cur][1][(wm + mt*16 + l)*32 + swz8];
#pragma unroll
        for (int nt = 0; nt < 4; ++nt)
            bf[nt] = *(half8*)&Bs[cur][1][(wn + nt*16 + l)*32 + swz8];
        __builtin_amdgcn_sched_barrier(0);
#pragma unroll
        for (int mt = 4; mt < 8; ++mt)
            af[mt] = *(half8*)&As[cur][1][(wm + mt*16 + l)*32 + swz8];
        if (pf) {
            gload_lds16(gb + ko + 32,                 &Bs[nxt][1][w*512]);
            gload_lds16(gb + ko + 32 + (size_t)128*K, &Bs[nxt][1][4096 + w*512]);
        }
        asm volatile("s_waitcnt lgkmcnt(4)" ::: "memory");
        __builtin_amdgcn_sched_barrier(0);
        __builtin_amdgcn_s_setprio(1);
#pragma unroll
        for (int mt = 0; mt < 4; ++mt)
#pragma unroll
            for (int nt = 0; nt < 4; ++nt)
                acc[mt][nt] = __builtin_amdgcn_mfma_f32_16x16x32_f16(af[mt], bf[nt], acc[mt][nt], 0, 0, 0);
        __builtin_amdgcn_s_setprio(0);
        asm volatile("s_waitcnt lgkmcnt(0)" ::: "memory");
        __builtin_amdgcn_sched_barrier(0);
        __builtin_amdgcn_s_setprio(1);
#pragma unroll
        for (int mt = 4; mt < 8; ++mt)
#pragma unroll
            for (int nt = 0; nt < 4; ++nt)
                acc[mt][nt] = __builtin_amdgcn_mfma_f32_16x16x32_f16(af[mt], bf[nt], acc[mt][nt], 0, 0, 0);
        __builtin_amdgcn_s_setprio(0);
    }

#pragma unroll
    for (int mt = 0; mt < 8; ++mt)
#pragma unroll
        for (int r = 0; r < 4; ++r) {
            size_t row = m0 + wm + mt*16 + quad*4 + r;
#pragma unroll
            for (int nt = 0; nt < 4; ++nt)
                C[row*N + n0 + wn + nt*16 + l] = (_Float16)acc[mt][nt][r];
        }
}

// ---------------------------------------------------------------------------
// gemm2: R6 core (128x256, tail-free 256 blocks), fp32 output + bias.
// ---------------------------------------------------------------------------
__global__ __launch_bounds__(512) void gemm2_f16(
    const _Float16* __restrict__ A, const _Float16* __restrict__ Bt,
    const float* __restrict__ bias, float* __restrict__ C, int M, int N, int K)
{
    __shared__ _Float16 As[2][2][4096] __attribute__((aligned(16)));
    __shared__ _Float16 Bs[2][2][8192] __attribute__((aligned(16)));

    const int tid  = threadIdx.x;
    const int w    = tid >> 6, lane = tid & 63, quad = lane >> 4, l = lane & 15;
    const int wm   = (w >> 2)*64, wn = (w & 3)*64;

    int bid = blockIdx.y*gridDim.x + blockIdx.x;
    const int per = (gridDim.x*gridDim.y) >> 3;
    bid = (bid & 7)*per + (bid >> 3);
    const int bx = bid % gridDim.x, by = bid / gridDim.x;
    const int m0 = by*128, n0 = bx*256;

    const int rs   = tid >> 2;
    const int csrc = (tid & 3) ^ ((tid >> 3) & 3);
    const _Float16* ga = A  + (size_t)(m0 + rs)*K + csrc*8;
    const _Float16* gb = Bt + (size_t)(n0 + rs)*K + csrc*8;
    const int swz8 = (quad ^ ((l >> 1) & 3))*8;

    floatx4 acc[4][4];
#pragma unroll
    for (int i = 0; i < 4; ++i)
#pragma unroll
        for (int j = 0; j < 4; ++j)
#pragma unroll
            for (int r = 0; r < 4; ++r) acc[i][j][r] = 0.f;

    gload_lds16(ga,                        &As[0][0][w*512]);
    gload_lds16(gb,                        &Bs[0][0][w*512]);
    gload_lds16(gb + (size_t)128*K,        &Bs[0][0][4096 + w*512]);
    gload_lds16(ga + 32,                   &As[0][1][w*512]);
    gload_lds16(gb + 32,                   &Bs[0][1][w*512]);
    gload_lds16(gb + 32 + (size_t)128*K,   &Bs[0][1][4096 + w*512]);

    const int KT = K / 64;
    for (int kt = 0; kt < KT; ++kt) {
        const int cur = kt & 1, nxt = cur ^ 1;
        const bool pf = (kt + 1 < KT);
        const size_t ko = (size_t)(kt + 1)*64;
        half8 af[4], bf[4];

        // ================= SP0 =================
        if (pf) gload_lds16(ga + ko, &As[nxt][0][w*512]);
        if (pf) { asm volatile("s_waitcnt vmcnt(4)" ::: "memory"); }
        else    { asm volatile("s_waitcnt vmcnt(3)" ::: "memory"); }
        __builtin_amdgcn_s_barrier();
        __builtin_amdgcn_sched_barrier(0);
#pragma unroll
        for (int mt = 0; mt < 4; ++mt)
            af[mt] = *(half8*)&As[cur][0][(wm + mt*16 + l)*32 + swz8];
#pragma unroll
        for (int nt = 0; nt < 4; ++nt)
            bf[nt] = *(half8*)&Bs[cur][0][(wn + nt*16 + l)*32 + swz8];
        if (pf) {
            gload_lds16(gb + ko,                 &Bs[nxt][0][w*512]);
            gload_lds16(gb + ko + (size_t)128*K, &Bs[nxt][0][4096 + w*512]);
        }
        asm volatile("s_waitcnt lgkmcnt(0)" ::: "memory");
        __builtin_amdgcn_sched_barrier(0);
        __builtin_amdgcn_s_setprio(1);
#pragma unroll
        for (int mt = 0; mt < 4; ++mt)
#pragma unroll
            for (int nt = 0; nt < 4; ++nt)
                acc[mt][nt] = __builtin_amdgcn_mfma_f32_16x16x32_f16(af[mt], bf[nt], acc[mt][nt], 0, 0, 0);
        __builtin_amdgcn_s_setprio(0);

        // ================= SP1 =================
        if (pf) gload_lds16(ga + ko + 32, &As[nxt][1][w*512]);
        if (pf) { asm volatile("s_waitcnt vmcnt(4)" ::: "memory"); }
        else    { asm volatile("s_waitcnt vmcnt(0)" ::: "memory"); }
        __builtin_amdgcn_s_barrier();
        __builtin_amdgcn_sched_barrier(0);
#pragma unroll
        for (int mt = 0; mt < 4; ++mt)
            af[mt] = *(half8*)&As[cur][1][(wm + mt*16 + l)*32 + swz8];
#pragma unroll
        for (int nt = 0; nt < 4; ++nt)
            bf[nt] = *(half8*)&Bs[cur][1][(wn + nt*16 + l)*32 + swz8];
        if (pf) {
            gload_lds16(gb + ko + 32,                 &Bs[nxt][1][w*512]);
            gload_lds16(gb + ko + 32 + (size_t)128*K, &Bs[nxt][1][4096 + w*512]);
        }
        asm volatile("s_waitcnt lgkmcnt(0)" ::: "memory");
        __builtin_amdgcn_sched_barrier(0);
        __builtin_amdgcn_s_setprio(1);
#pragma unroll
        for (int mt = 0; mt < 4; ++mt)
#pragma unroll
            for (int nt = 0; nt < 4; ++nt)
                acc[mt][nt] = __builtin_amdgcn_mfma_f32_16x16x32_f16(af[mt], bf[nt], acc[mt][nt], 0, 0, 0);
        __builtin_amdgcn_s_setprio(0);
    }

#pragma unroll
    for (int mt = 0; mt < 4; ++mt)
#pragma unroll
        for (int r = 0; r < 4; ++r) {
            size_t row = m0 + wm + mt*16 + quad*4 + r;
#pragma unroll
            for (int nt = 0; nt < 4; ++nt) {
                int col = n0 + wn + nt*16 + l;
                C[row*N + col] = acc[mt][nt][r] + bias[col];
            }
        }
}

// ---------------------------------------------------------------------------
// rope + scatter. q pre-scaled by (1/8)*log2e so attention exp is bare exp2.
// ---------------------------------------------------------------------------
__global__ __launch_bounds__(256) void rope_scatter(
    const _Float16* __restrict__ qkv,
    _Float16* __restrict__ qw, _Float16* __restrict__ kw,
    _Float16* __restrict__ vt)
{
    const int sc = blockIdx.x;
    const int bh = blockIdx.y;
    const int bt = bh >> 4, head = bh & 15;
    const int s0 = sc*64;
    const int tid = threadIdx.x;
    const int d0 = (tid & 7)*8;

    __shared__ _Float16 T[64][80];

#pragma unroll
    for (int half = 0; half < 2; ++half) {
        const int r = (tid >> 3) + half*32;
        const int s = s0 + r;
        const _Float16* src = qkv + (size_t)(bt*SEQ + s)*NQKV + head*DH + d0;
        half8 hq = *(const half8*)(src);
        half8 hk = *(const half8*)(src + DMODEL);
        half8 hv = *(const half8*)(src + 2*DMODEL);
        float fq[8], fk[8];
#pragma unroll
        for (int j = 0; j < 8; ++j) { fq[j] = (float)hq[j]; fk[j] = (float)hk[j]; }
        const int hp = s >> 5, wp = s & 31;
        const float ph = -1.0f + hp*(2.0f/31.0f);
        const float pw = -1.0f + wp*(2.0f/31.0f);
#pragma unroll
        for (int p = 0; p < 4; ++p) {
            int pg = (d0 >> 1) + p;
            float pos = (pg < 16) ? ph : pw;
            int   gi  = (pg < 16) ? pg : (pg - 16);
            float th  = pos * ((1.0f + gi*(127.0f/15.0f)) * PI_F);
            float sn, cs;
            sincosf(th, &sn, &cs);
            float q1 = fq[2*p], q2 = fq[2*p+1];
            fq[2*p]   = q1*cs - q2*sn;
            fq[2*p+1] = q2*cs + q1*sn;
            float k1 = fk[2*p], k2 = fk[2*p+1];
            fk[2*p]   = k1*cs - k2*sn;
            fk[2*p+1] = k2*cs + k1*sn;
        }
        half8 oq, ok;
        const float qsc = 0.125f * LOG2E;
#pragma unroll
        for (int j = 0; j < 8; ++j) {
            oq[j] = (_Float16)(fq[j]*qsc);
            ok[j] = (_Float16)fk[j];
        }
        *(half8*)(qw + (size_t)bh*HS + (size_t)s*DH + d0) = oq;
        *(half8*)(kw + (size_t)bh*HS + (size_t)s*DH + d0) = ok;
#pragma unroll
        for (int j = 0; j < 8; ++j) T[d0 + j][r] = hv[j];
    }
    __syncthreads();
    const int d = tid >> 2, so = (tid & 3)*16;
    half8 v0 = *(half8*)&T[d][so];
    half8 v1 = *(half8*)&T[d][so + 8];
    _Float16* dst = vt + (size_t)bh*HS + (size_t)d*SEQ + s0 + so;
    *(half8*)dst       = v0;
    *(half8*)(dst + 8) = v1;
}

// ---------------------------------------------------------------------------
// Flash attention v6: BQ=256 per block, 8 waves x 32 queries (2 q-tiles).
// Same per-wave structure as harness-verified v4, but 8 waves share each
// K/V chunk -> 4 waves/SIMD (was 2) to hide the serial
// QK->exp2->Pstore->Pread->PV chain; K/V HBM staging halved vs BQ=128.
// LDS 70.6KB -> 2 blocks/CU. Fused QK->exp2->P-store keeps VGPR low.
// ---------------------------------------------------------------------------
#define BC  64
#define LDH 68     // padded row stride (halfwords): rows shift 2 banks; <=2-way on frags

__global__ __launch_bounds__(512) void attn_mfma(
    const _Float16* __restrict__ qw, const _Float16* __restrict__ kw,
    const _Float16* __restrict__ vt, _Float16* __restrict__ om)
{
    const int qc = blockIdx.x;    // 0..3  (256-query chunk)
    const int bh = blockIdx.y;    // 0..127
    const int tid  = threadIdx.x;
    const int w    = tid >> 6;    // 0..7
    const int lane = tid & 63;
    const int quad = lane >> 4;
    const int l    = lane & 15;

    __shared__ _Float16 Ks[2][BC][LDH];
    __shared__ _Float16 Vs[2][DH][LDH];
    __shared__ _Float16 Ps[8][32][LDH];
    __shared__ float    Ls[8][32];

    const _Float16* qp = qw + (size_t)bh*HS + (size_t)(qc*256 + w*32)*DH;
    const _Float16* kp = kw + (size_t)bh*HS;
    const _Float16* vp = vt + (size_t)bh*HS;   // [d][1024]

    // Q B-frags for this wave's 2 q-tiles (held all loop)
    half8 qf[2][2];
#pragma unroll
    for (int qt = 0; qt < 2; ++qt) {
        qf[qt][0] = *(const half8*)(qp + (size_t)(qt*16 + l)*DH + quad*8);
        qf[qt][1] = *(const half8*)(qp + (size_t)(qt*16 + l)*DH + quad*8 + 32);
    }

    // staging: 512 threads cover 64 rows x 8 col-chunks, 1 K + 1 V load each
    const int rs = tid >> 3;           // 0..63
    const int cs = (tid & 7)*8;        // 0..56

    half8 kr = *(const half8*)(kp + (size_t)rs*DH + cs);
    half8 vr = *(const half8*)(vp + (size_t)rs*SEQ + cs);
    *(half8*)&Ks[0][rs][cs] = kr;
    *(half8*)&Vs[0][rs][cs] = vr;

    floatx4 Of[2][4];
#pragma unroll
    for (int qt = 0; qt < 2; ++qt)
#pragma unroll
        for (int dt = 0; dt < 4; ++dt)
#pragma unroll
            for (int r = 0; r < 4; ++r) Of[qt][dt][r] = 0.f;
    float lsum[2] = {0.f, 0.f};

    __syncthreads();

    for (int kc = 0; kc < SEQ/BC; ++kc) {
        const int cur = kc & 1;
        // prefetch chunk kc+1 into registers (hides under compute)
        if (kc < SEQ/BC - 1) {
            const _Float16* kn = kp + (size_t)(kc+1)*BC*DH;
            const _Float16* vn = vp + (size_t)(kc+1)*BC;
            kr = *(const half8*)(kn + (size_t)rs*DH + cs);
            vr = *(const half8*)(vn + (size_t)rs*SEQ + cs);
        }

        // S^T = K.Q^T, fused exp2 + P store per (kg, qt); one S tile live
#pragma unroll
        for (int kg = 0; kg < 4; ++kg) {
            half8 af0 = *(half8*)&Ks[cur][kg*16 + l][quad*8];
            half8 af1 = *(half8*)&Ks[cur][kg*16 + l][quad*8 + 32];
#pragma unroll
            for (int qt = 0; qt < 2; ++qt) {
                floatx4 a;
#pragma unroll
                for (int r = 0; r < 4; ++r) a[r] = 0.f;
                a = __builtin_amdgcn_mfma_f32_16x16x32_f16(af0, qf[qt][0], a, 0, 0, 0);
                a = __builtin_amdgcn_mfma_f32_16x16x32_f16(af1, qf[qt][1], a, 0, 0, 0);
                half4 p4;
#pragma unroll
                for (int r = 0; r < 4; ++r) {
                    float p = __builtin_amdgcn_exp2f(a[r]);
                    lsum[qt] += p;
                    p4[r] = (_Float16)p;
                }
                *(half4*)&Ps[w][qt*16 + l][kg*16 + quad*4] = p4;
            }
        }
        // PV: A = P b128 frags (wave-private), B = V^T (read once, 2x reuse)
        half8 pa[2][2];
#pragma unroll
        for (int qt = 0; qt < 2; ++qt) {
            pa[qt][0] = *(half8*)&Ps[w][qt*16 + l][quad*8];
            pa[qt][1] = *(half8*)&Ps[w][qt*16 + l][quad*8 + 32];
        }
#pragma unroll
        for (int dt = 0; dt < 4; ++dt) {
            half8 vb0 = *(half8*)&Vs[cur][dt*16 + l][quad*8];
            half8 vb1 = *(half8*)&Vs[cur][dt*16 + l][quad*8 + 32];
#pragma unroll
            for (int qt = 0; qt < 2; ++qt) {
                Of[qt][dt] = __builtin_amdgcn_mfma_f32_16x16x32_f16(pa[qt][0], vb0, Of[qt][dt], 0, 0, 0);
                Of[qt][dt] = __builtin_amdgcn_mfma_f32_16x16x32_f16(pa[qt][1], vb1, Of[qt][dt], 0, 0, 0);
            }
        }

        // commit prefetched chunk to the other buffer, single barrier
        if (kc < SEQ/BC - 1) {
            *(half8*)&Ks[1-cur][rs][cs] = kr;
            *(half8*)&Vs[1-cur][rs][cs] = vr;
        }
        __syncthreads();
    }

    // final l: reduce across quads, redistribute via per-wave LDS
#pragma unroll
    for (int qt = 0; qt < 2; ++qt) {
        lsum[qt] += __shfl_xor(lsum[qt], 16);
        lsum[qt] += __shfl_xor(lsum[qt], 32);
        if (quad == 0) Ls[w][qt*16 + l] = lsum[qt];
    }
    const int bt = bh >> 4, head = bh & 15;
    _Float16* opf = om + (size_t)(bt*SEQ + qc*256 + w*32)*DMODEL + head*DH;
#pragma unroll
    for (int qt = 0; qt < 2; ++qt) {
        float inv[4];
#pragma unroll
        for (int r = 0; r < 4; ++r) inv[r] = 1.0f / Ls[w][qt*16 + quad*4 + r];
#pragma unroll
        for (int dt = 0; dt < 4; ++dt)
#pragma unroll
            for (int r = 0; r < 4; ++r)
                opf[(size_t)(qt*16 + quad*4 + r)*DMODEL + dt*16 + l] =
                    (_Float16)(Of[qt][dt][r]*inv[r]);
    }
}

// ---------------------------------------------------------------------------
extern "C" void kernel_launch(void* const* d_in, const int* in_sizes, int n_in,
                              void* d_out, int out_size, void* d_ws, size_t ws_size,
                              hipStream_t stream)
{
    const float* x    = (const float*)d_in[0];
    const float* Wqkv = (const float*)d_in[1];
    const float* Wout = (const float*)d_in[2];
    const float* bout = (const float*)d_in[3];
    float* out = (float*)d_out;

    _Float16* ws   = (_Float16*)d_ws;
    _Float16* Xh   = ws;                  // 8388608
    _Float16* Wqkt = ws + 8388608;        // 3145728  [3072][1024]
    _Float16* Wot  = ws + 11534336;       // 1048576  [1024][1024]
    _Float16* qkvt = ws + 12582912;       // 25165824 [8192][3072]
    _Float16* qw   = ws + 37748736;       // 8388608
    _Float16* kw   = ws + 46137344;       // 8388608
    _Float16* vt   = ws + 54525952;       // 8388608  (end: 120 MiB)
    _Float16* om   = qkvt;                // alias: reused after rope_scatter

    hipLaunchKernelGGL(cvt_f16, dim3(4096), dim3(256), 0, stream,
                       x, Xh, 8388608);
    hipLaunchKernelGGL(tr_cvt, dim3(96, 32), dim3(256), 0, stream,
                       Wqkv, Wqkt, 1024, 3072);
    hipLaunchKernelGGL(tr_cvt, dim3(32, 32), dim3(256), 0, stream,
                       Wout, Wot, 1024, 1024);
    hipLaunchKernelGGL(gemm1_f16, dim3(12, 32), dim3(512), 0, stream,
                       Xh, Wqkt, qkvt, 8192, NQKV, DMODEL);
    hipLaunchKernelGGL(rope_scatter, dim3(16, 128), dim3(256), 0, stream,
                       qkvt, qw, kw, vt);
    hipLaunchKernelGGL(attn_mfma, dim3(4, 128), dim3(512), 0, stream,
                       qw, kw, vt, om);
    hipLaunchKernelGGL(gemm2_f16, dim3(4, 64), dim3(512), 0, stream,
                       om, Wot, bout, out, 8192, DMODEL, DMODEL);
}

// Round 9
// 247.288 us; speedup vs baseline: 1.0674x; 1.0015x over previous
//
#include <hip/hip_runtime.h>
#include <math.h>

#define DMODEL 1024
#define NQKV   3072
#define SEQ    1024
#define NH     16
#define DH     64
#define HS     (SEQ*DH)
constexpr float PI_F   = 3.14159265358979323846f;
constexpr float LOG2E  = 1.44269504088896f;

typedef _Float16 half8   __attribute__((ext_vector_type(8)));
typedef _Float16 half4   __attribute__((ext_vector_type(4)));
typedef float    floatx4 __attribute__((ext_vector_type(4)));

// async global->LDS, 16B per lane; LDS dest is wave-uniform base + lane*16
__device__ __forceinline__ void gload_lds16(const _Float16* g, _Float16* l) {
    __builtin_amdgcn_global_load_lds(
        (const __attribute__((address_space(1))) unsigned int*)g,
        (__attribute__((address_space(3)))       unsigned int*)l,
        16, 0, 0);
}

// ---------------------------------------------------------------------------
// flat fp32 -> f16 convert
// ---------------------------------------------------------------------------
__global__ __launch_bounds__(256) void cvt_f16(
    const float* __restrict__ in, _Float16* __restrict__ out, int n)
{
    int i = (blockIdx.x*256 + threadIdx.x)*8;
    if (i >= n) return;
    float4 a = *(const float4*)(in + i);
    float4 b = *(const float4*)(in + i + 4);
    half8 h;
    h[0]=(_Float16)a.x; h[1]=(_Float16)a.y; h[2]=(_Float16)a.z; h[3]=(_Float16)a.w;
    h[4]=(_Float16)b.x; h[5]=(_Float16)b.y; h[6]=(_Float16)b.z; h[7]=(_Float16)b.w;
    *(half8*)(out + i) = h;
}

// ---------------------------------------------------------------------------
// transpose + convert: in [R][C] fp32 -> out [C][R] f16   (32x32 tiles)
// ---------------------------------------------------------------------------
__global__ __launch_bounds__(256) void tr_cvt(
    const float* __restrict__ in, _Float16* __restrict__ out, int R, int C)
{
    __shared__ float T[32][33];
    const int bx = blockIdx.x, by = blockIdx.y;
    const int tx = threadIdx.x & 31, ty = threadIdx.x >> 5;
#pragma unroll
    for (int i = 0; i < 4; ++i)
        T[ty + i*8][tx] = in[(size_t)(by*32 + ty + i*8)*C + bx*32 + tx];
    __syncthreads();
#pragma unroll
    for (int i = 0; i < 4; ++i)
        out[(size_t)(bx*32 + ty + i*8)*R + by*32 + tx] = (_Float16)T[tx][ty + i*8];
}

// ---------------------------------------------------------------------------
// gemm1: R2 measured-best. 256x256 tile, BK=64 as 2 k-halves,
// 8 waves (2Mx4N, 128x64/wave). Counted-vmcnt 2-super-phase schedule.
// Grid 12x32=384.
// ---------------------------------------------------------------------------
__global__ __launch_bounds__(512) void gemm1_f16(
    const _Float16* __restrict__ A, const _Float16* __restrict__ Bt,
    _Float16* __restrict__ C, int M, int N, int K)
{
    __shared__ _Float16 As[2][2][8192] __attribute__((aligned(16)));
    __shared__ _Float16 Bs[2][2][8192] __attribute__((aligned(16)));

    const int tid  = threadIdx.x;
    const int w    = tid >> 6, lane = tid & 63, quad = lane >> 4, l = lane & 15;
    const int wm   = (w >> 2)*128, wn = (w & 3)*64;

    int bid = blockIdx.y*gridDim.x + blockIdx.x;
    const int per = (gridDim.x*gridDim.y) >> 3;
    bid = (bid & 7)*per + (bid >> 3);
    const int bx = bid % gridDim.x, by = bid / gridDim.x;
    const int m0 = by*256, n0 = bx*256;

    const int rs   = tid >> 2;
    const int csrc = (tid & 3) ^ ((tid >> 3) & 3);
    const _Float16* ga = A  + (size_t)(m0 + rs)*K + csrc*8;
    const _Float16* gb = Bt + (size_t)(n0 + rs)*K + csrc*8;
    const int swz8 = (quad ^ ((l >> 1) & 3))*8;

    floatx4 acc[8][4];
#pragma unroll
    for (int i = 0; i < 8; ++i)
#pragma unroll
        for (int j = 0; j < 4; ++j)
#pragma unroll
            for (int r = 0; r < 4; ++r) acc[i][j][r] = 0.f;

    // prologue: tile 0, order A-k0(2), B-k0(2), A-k1(2), B-k1(2)
    gload_lds16(ga,                      &As[0][0][w*512]);
    gload_lds16(ga + (size_t)128*K,      &As[0][0][4096 + w*512]);
    gload_lds16(gb,                      &Bs[0][0][w*512]);
    gload_lds16(gb + (size_t)128*K,      &Bs[0][0][4096 + w*512]);
    gload_lds16(ga + 32,                 &As[0][1][w*512]);
    gload_lds16(ga + 32 + (size_t)128*K, &As[0][1][4096 + w*512]);
    gload_lds16(gb + 32,                 &Bs[0][1][w*512]);
    gload_lds16(gb + 32 + (size_t)128*K, &Bs[0][1][4096 + w*512]);

    const int KT = K / 64;
    for (int kt = 0; kt < KT; ++kt) {
        const int cur = kt & 1, nxt = cur ^ 1;
        const bool pf = (kt + 1 < KT);
        const size_t ko = (size_t)(kt + 1)*64;
        half8 af[8], bf[4];

        // ================= SP0 : k-half 0 =================
        if (pf) {
            gload_lds16(ga + ko,                 &As[nxt][0][w*512]);
            gload_lds16(ga + ko + (size_t)128*K, &As[nxt][0][4096 + w*512]);
        }
        if (pf) { asm volatile("s_waitcnt vmcnt(6)" ::: "memory"); }
        else    { asm volatile("s_waitcnt vmcnt(4)" ::: "memory"); }
        __builtin_amdgcn_s_barrier();
        __builtin_amdgcn_sched_barrier(0);
#pragma unroll
        for (int mt = 0; mt < 4; ++mt)
            af[mt] = *(half8*)&As[cur][0][(wm + mt*16 + l)*32 + swz8];
#pragma unroll
        for (int nt = 0; nt < 4; ++nt)
            bf[nt] = *(half8*)&Bs[cur][0][(wn + nt*16 + l)*32 + swz8];
        __builtin_amdgcn_sched_barrier(0);
#pragma unroll
        for (int mt = 4; mt < 8; ++mt)
            af[mt] = *(half8*)&As[cur][0][(wm + mt*16 + l)*32 + swz8];
        if (pf) {
            gload_lds16(gb + ko,                 &Bs[nxt][0][w*512]);
            gload_lds16(gb + ko + (size_t)128*K, &Bs[nxt][0][4096 + w*512]);
        }
        asm volatile("s_waitcnt lgkmcnt(4)" ::: "memory");
        __builtin_amdgcn_sched_barrier(0);
        __builtin_amdgcn_s_setprio(1);
#pragma unroll
        for (int mt = 0; mt < 4; ++mt)
#pragma unroll
            for (int nt = 0; nt < 4; ++nt)
                acc[mt][nt] = __builtin_amdgcn_mfma_f32_16x16x32_f16(af[mt], bf[nt], acc[mt][nt], 0, 0, 0);
        __builtin_amdgcn_s_setprio(0);
        asm volatile("s_waitcnt lgkmcnt(0)" ::: "memory");
        __builtin_amdgcn_sched_barrier(0);
        __builtin_amdgcn_s_setprio(1);
#pragma unroll
        for (int mt = 4; mt < 8; ++mt)
#pragma unroll
            for (int nt = 0; nt < 4; ++nt)
                acc[mt][nt] = __builtin_amdgcn_mfma_f32_16x16x32_f16(af[mt], bf[nt], acc[mt][nt], 0, 0, 0);
        __builtin_amdgcn_s_setprio(0);

        // ================= SP1 : k-half 1 =================
        if (pf) {
            gload_lds16(ga + ko + 32,                 &As[nxt][1][w*512]);
            gload_lds16(ga + ko + 32 + (size_t)128*K, &As[nxt][1][4096 + w*512]);
        }
        if (pf) { asm volatile("s_waitcnt vmcnt(6)" ::: "memory"); }
        else    { asm volatile("s_waitcnt vmcnt(0)" ::: "memory"); }
        __builtin_amdgcn_s_barrier();
        __builtin_amdgcn_sched_barrier(0);
#pragma unroll
        for (int mt = 0; mt < 4; ++mt)
            af[mt] = *(half8*)&As[cur][1][(wm + mt*16 + l)*32 + swz8];
#pragma unroll
        for (int nt = 0; nt < 4; ++nt)
            bf[nt] = *(half8*)&Bs[cur][1][(wn + nt*16 + l)*32 + swz8];
        __builtin_amdgcn_sched_barrier(0);
#pragma unroll
        for (int mt = 4; mt < 8; ++mt)
            af[mt] = *(half8*)&As[cur][1][(wm + mt*16 + l)*32 + swz8];
        if (pf) {
            gload_lds16(gb + ko + 32,                 &Bs[nxt][1][w*512]);
            gload_lds16(gb + ko + 32 + (size_t)128*K, &Bs[nxt][1][4096 + w*512]);
        }
        asm volatile("s_waitcnt lgkmcnt(4)" ::: "memory");
        __builtin_amdgcn_sched_barrier(0);
        __builtin_amdgcn_s_setprio(1);
#pragma unroll
        for (int mt = 0; mt < 4; ++mt)
#pragma unroll
            for (int nt = 0; nt < 4; ++nt)
                acc[mt][nt] = __builtin_amdgcn_mfma_f32_16x16x32_f16(af[mt], bf[nt], acc[mt][nt], 0, 0, 0);
        __builtin_amdgcn_s_setprio(0);
        asm volatile("s_waitcnt lgkmcnt(0)" ::: "memory");
        __builtin_amdgcn_sched_barrier(0);
        __builtin_amdgcn_s_setprio(1);
#pragma unroll
        for (int mt = 4; mt < 8; ++mt)
#pragma unroll
            for (int nt = 0; nt < 4; ++nt)
                acc[mt][nt] = __builtin_amdgcn_mfma_f32_16x16x32_f16(af[mt], bf[nt], acc[mt][nt], 0, 0, 0);
        __builtin_amdgcn_s_setprio(0);
    }

#pragma unroll
    for (int mt = 0; mt < 8; ++mt)
#pragma unroll
        for (int r = 0; r < 4; ++r) {
            size_t row = m0 + wm + mt*16 + quad*4 + r;
#pragma unroll
            for (int nt = 0; nt < 4; ++nt)
                C[row*N + n0 + wn + nt*16 + l] = (_Float16)acc[mt][nt][r];
        }
}

// ---------------------------------------------------------------------------
// gemm2 v2: 128x128 tile, BK=64 as 2 k-halves, 8 waves (2Mx4N, 64x32/wave).
// LDS 64KB -> 2 blocks/CU = 4 waves/SIMD (was 1 block/96KB = 2/SIMD).
// Grid 8x64 = 512 = 2x256, zero tail. Same sync skeleton; 1-gload stages,
// ledger (FIFO): stage order/tile A0' B0' A1' B1'; SP0 gate retires thru
// B0^t -> vmcnt(3) (last 2); SP1 gate retires thru B1^t -> vmcnt(3) (last 0).
// fp32 output + bias.
// ---------------------------------------------------------------------------
__global__ __launch_bounds__(512) void gemm2_f16(
    const _Float16* __restrict__ A, const _Float16* __restrict__ Bt,
    const float* __restrict__ bias, float* __restrict__ C, int M, int N, int K)
{
    __shared__ _Float16 As[2][2][4096] __attribute__((aligned(16)));
    __shared__ _Float16 Bs[2][2][4096] __attribute__((aligned(16)));

    const int tid  = threadIdx.x;
    const int w    = tid >> 6, lane = tid & 63, quad = lane >> 4, l = lane & 15;
    const int wm   = (w >> 2)*64, wn = (w & 3)*32;

    int bid = blockIdx.y*gridDim.x + blockIdx.x;
    const int per = (gridDim.x*gridDim.y) >> 3;
    bid = (bid & 7)*per + (bid >> 3);
    const int bx = bid % gridDim.x, by = bid / gridDim.x;
    const int m0 = by*128, n0 = bx*128;

    const int rs   = tid >> 2;
    const int csrc = (tid & 3) ^ ((tid >> 3) & 3);
    const _Float16* ga = A  + (size_t)(m0 + rs)*K + csrc*8;
    const _Float16* gb = Bt + (size_t)(n0 + rs)*K + csrc*8;
    const int swz8 = (quad ^ ((l >> 1) & 3))*8;

    floatx4 acc[4][2];
#pragma unroll
    for (int i = 0; i < 4; ++i)
#pragma unroll
        for (int j = 0; j < 2; ++j)
#pragma unroll
            for (int r = 0; r < 4; ++r) acc[i][j][r] = 0.f;

    // prologue: tile 0, order A-k0, B-k0, A-k1, B-k1 (4 gloads/thread)
    gload_lds16(ga,      &As[0][0][w*512]);
    gload_lds16(gb,      &Bs[0][0][w*512]);
    gload_lds16(ga + 32, &As[0][1][w*512]);
    gload_lds16(gb + 32, &Bs[0][1][w*512]);

    const int KT = K / 64;
    for (int kt = 0; kt < KT; ++kt) {
        const int cur = kt & 1, nxt = cur ^ 1;
        const bool pf = (kt + 1 < KT);
        const size_t ko = (size_t)(kt + 1)*64;
        half8 af[4], bf[2];

        // ================= SP0 : k-half 0 =================
        if (pf) gload_lds16(ga + ko, &As[nxt][0][w*512]);
        if (pf) { asm volatile("s_waitcnt vmcnt(3)" ::: "memory"); }
        else    { asm volatile("s_waitcnt vmcnt(2)" ::: "memory"); }
        __builtin_amdgcn_s_barrier();
        __builtin_amdgcn_sched_barrier(0);
#pragma unroll
        for (int mt = 0; mt < 4; ++mt)
            af[mt] = *(half8*)&As[cur][0][(wm + mt*16 + l)*32 + swz8];
#pragma unroll
        for (int nt = 0; nt < 2; ++nt)
            bf[nt] = *(half8*)&Bs[cur][0][(wn + nt*16 + l)*32 + swz8];
        if (pf) gload_lds16(gb + ko, &Bs[nxt][0][w*512]);
        asm volatile("s_waitcnt lgkmcnt(0)" ::: "memory");
        __builtin_amdgcn_sched_barrier(0);
        __builtin_amdgcn_s_setprio(1);
#pragma unroll
        for (int mt = 0; mt < 4; ++mt)
#pragma unroll
            for (int nt = 0; nt < 2; ++nt)
                acc[mt][nt] = __builtin_amdgcn_mfma_f32_16x16x32_f16(af[mt], bf[nt], acc[mt][nt], 0, 0, 0);
        __builtin_amdgcn_s_setprio(0);

        // ================= SP1 : k-half 1 =================
        if (pf) gload_lds16(ga + ko + 32, &As[nxt][1][w*512]);
        if (pf) { asm volatile("s_waitcnt vmcnt(3)" ::: "memory"); }
        else    { asm volatile("s_waitcnt vmcnt(0)" ::: "memory"); }
        __builtin_amdgcn_s_barrier();
        __builtin_amdgcn_sched_barrier(0);
#pragma unroll
        for (int mt = 0; mt < 4; ++mt)
            af[mt] = *(half8*)&As[cur][1][(wm + mt*16 + l)*32 + swz8];
#pragma unroll
        for (int nt = 0; nt < 2; ++nt)
            bf[nt] = *(half8*)&Bs[cur][1][(wn + nt*16 + l)*32 + swz8];
        if (pf) gload_lds16(gb + ko + 32, &Bs[nxt][1][w*512]);
        asm volatile("s_waitcnt lgkmcnt(0)" ::: "memory");
        __builtin_amdgcn_sched_barrier(0);
        __builtin_amdgcn_s_setprio(1);
#pragma unroll
        for (int mt = 0; mt < 4; ++mt)
#pragma unroll
            for (int nt = 0; nt < 2; ++nt)
                acc[mt][nt] = __builtin_amdgcn_mfma_f32_16x16x32_f16(af[mt], bf[nt], acc[mt][nt], 0, 0, 0);
        __builtin_amdgcn_s_setprio(0);
    }

#pragma unroll
    for (int mt = 0; mt < 4; ++mt)
#pragma unroll
        for (int r = 0; r < 4; ++r) {
            size_t row = m0 + wm + mt*16 + quad*4 + r;
#pragma unroll
            for (int nt = 0; nt < 2; ++nt) {
                int col = n0 + wn + nt*16 + l;
                C[row*N + col] = acc[mt][nt][r] + bias[col];
            }
        }
}

// ---------------------------------------------------------------------------
// rope + scatter. q pre-scaled by (1/8)*log2e so attention exp is bare exp2.
// ---------------------------------------------------------------------------
__global__ __launch_bounds__(256) void rope_scatter(
    const _Float16* __restrict__ qkv,
    _Float16* __restrict__ qw, _Float16* __restrict__ kw,
    _Float16* __restrict__ vt)
{
    const int sc = blockIdx.x;
    const int bh = blockIdx.y;
    const int bt = bh >> 4, head = bh & 15;
    const int s0 = sc*64;
    const int tid = threadIdx.x;
    const int d0 = (tid & 7)*8;

    __shared__ _Float16 T[64][80];

#pragma unroll
    for (int half = 0; half < 2; ++half) {
        const int r = (tid >> 3) + half*32;
        const int s = s0 + r;
        const _Float16* src = qkv + (size_t)(bt*SEQ + s)*NQKV + head*DH + d0;
        half8 hq = *(const half8*)(src);
        half8 hk = *(const half8*)(src + DMODEL);
        half8 hv = *(const half8*)(src + 2*DMODEL);
        float fq[8], fk[8];
#pragma unroll
        for (int j = 0; j < 8; ++j) { fq[j] = (float)hq[j]; fk[j] = (float)hk[j]; }
        const int hp = s >> 5, wp = s & 31;
        const float ph = -1.0f + hp*(2.0f/31.0f);
        const float pw = -1.0f + wp*(2.0f/31.0f);
#pragma unroll
        for (int p = 0; p < 4; ++p) {
            int pg = (d0 >> 1) + p;
            float pos = (pg < 16) ? ph : pw;
            int   gi  = (pg < 16) ? pg : (pg - 16);
            float th  = pos * ((1.0f + gi*(127.0f/15.0f)) * PI_F);
            float sn, cs;
            sincosf(th, &sn, &cs);
            float q1 = fq[2*p], q2 = fq[2*p+1];
            fq[2*p]   = q1*cs - q2*sn;
            fq[2*p+1] = q2*cs + q1*sn;
            float k1 = fk[2*p], k2 = fk[2*p+1];
            fk[2*p]   = k1*cs - k2*sn;
            fk[2*p+1] = k2*cs + k1*sn;
        }
        half8 oq, ok;
        const float qsc = 0.125f * LOG2E;
#pragma unroll
        for (int j = 0; j < 8; ++j) {
            oq[j] = (_Float16)(fq[j]*qsc);
            ok[j] = (_Float16)fk[j];
        }
        *(half8*)(qw + (size_t)bh*HS + (size_t)s*DH + d0) = oq;
        *(half8*)(kw + (size_t)bh*HS + (size_t)s*DH + d0) = ok;
#pragma unroll
        for (int j = 0; j < 8; ++j) T[d0 + j][r] = hv[j];
    }
    __syncthreads();
    const int d = tid >> 2, so = (tid & 3)*16;
    half8 v0 = *(half8*)&T[d][so];
    half8 v1 = *(half8*)&T[d][so + 8];
    _Float16* dst = vt + (size_t)bh*HS + (size_t)d*SEQ + s0 + so;
    *(half8*)dst       = v0;
    *(half8*)(dst + 8) = v1;
}

// ---------------------------------------------------------------------------
// Flash attention v6: BQ=256 per block, 8 waves x 32 queries (2 q-tiles).
// 8 waves share each K/V chunk -> 4 waves/SIMD hides the serial
// QK->exp2->Pstore->Pread->PV chain. launch_bounds(512,4) pins the
// 128-VGPR / 4-waves-per-SIMD operating point the R8 win depends on.
// ---------------------------------------------------------------------------
#define BC  64
#define LDH 68     // padded row stride (halfwords): rows shift 2 banks; <=2-way on frags

__global__ __launch_bounds__(512, 4) void attn_mfma(
    const _Float16* __restrict__ qw, const _Float16* __restrict__ kw,
    const _Float16* __restrict__ vt, _Float16* __restrict__ om)
{
    const int qc = blockIdx.x;    // 0..3  (256-query chunk)
    const int bh = blockIdx.y;    // 0..127
    const int tid  = threadIdx.x;
    const int w    = tid >> 6;    // 0..7
    const int lane = tid & 63;
    const int quad = lane >> 4;
    const int l    = lane & 15;

    __shared__ _Float16 Ks[2][BC][LDH];
    __shared__ _Float16 Vs[2][DH][LDH];
    __shared__ _Float16 Ps[8][32][LDH];
    __shared__ float    Ls[8][32];

    const _Float16* qp = qw + (size_t)bh*HS + (size_t)(qc*256 + w*32)*DH;
    const _Float16* kp = kw + (size_t)bh*HS;
    const _Float16* vp = vt + (size_t)bh*HS;   // [d][1024]

    // Q B-frags for this wave's 2 q-tiles (held all loop)
    half8 qf[2][2];
#pragma unroll
    for (int qt = 0; qt < 2; ++qt) {
        qf[qt][0] = *(const half8*)(qp + (size_t)(qt*16 + l)*DH + quad*8);
        qf[qt][1] = *(const half8*)(qp + (size_t)(qt*16 + l)*DH + quad*8 + 32);
    }

    // staging: 512 threads cover 64 rows x 8 col-chunks, 1 K + 1 V load each
    const int rs = tid >> 3;           // 0..63
    const int cs = (tid & 7)*8;        // 0..56

    half8 kr = *(const half8*)(kp + (size_t)rs*DH + cs);
    half8 vr = *(const half8*)(vp + (size_t)rs*SEQ + cs);
    *(half8*)&Ks[0][rs][cs] = kr;
    *(half8*)&Vs[0][rs][cs] = vr;

    floatx4 Of[2][4];
#pragma unroll
    for (int qt = 0; qt < 2; ++qt)
#pragma unroll
        for (int dt = 0; dt < 4; ++dt)
#pragma unroll
            for (int r = 0; r < 4; ++r) Of[qt][dt][r] = 0.f;
    float lsum[2] = {0.f, 0.f};

    __syncthreads();

    for (int kc = 0; kc < SEQ/BC; ++kc) {
        const int cur = kc & 1;
        // prefetch chunk kc+1 into registers (hides under compute)
        if (kc < SEQ/BC - 1) {
            const _Float16* kn = kp + (size_t)(kc+1)*BC*DH;
            const _Float16* vn = vp + (size_t)(kc+1)*BC;
            kr = *(const half8*)(kn + (size_t)rs*DH + cs);
            vr = *(const half8*)(vn + (size_t)rs*SEQ + cs);
        }

        // S^T = K.Q^T, fused exp2 + P store per (kg, qt); one S tile live
#pragma unroll
        for (int kg = 0; kg < 4; ++kg) {
            half8 af0 = *(half8*)&Ks[cur][kg*16 + l][quad*8];
            half8 af1 = *(half8*)&Ks[cur][kg*16 + l][quad*8 + 32];
#pragma unroll
            for (int qt = 0; qt < 2; ++qt) {
                floatx4 a;
#pragma unroll
                for (int r = 0; r < 4; ++r) a[r] = 0.f;
                a = __builtin_amdgcn_mfma_f32_16x16x32_f16(af0, qf[qt][0], a, 0, 0, 0);
                a = __builtin_amdgcn_mfma_f32_16x16x32_f16(af1, qf[qt][1], a, 0, 0, 0);
                half4 p4;
#pragma unroll
                for (int r = 0; r < 4; ++r) {
                    float p = __builtin_amdgcn_exp2f(a[r]);
                    lsum[qt] += p;
                    p4[r] = (_Float16)p;
                }
                *(half4*)&Ps[w][qt*16 + l][kg*16 + quad*4] = p4;
            }
        }
        // PV: A = P b128 frags (wave-private), B = V^T (read once, 2x reuse)
        half8 pa[2][2];
#pragma unroll
        for (int qt = 0; qt < 2; ++qt) {
            pa[qt][0] = *(half8*)&Ps[w][qt*16 + l][quad*8];
            pa[qt][1] = *(half8*)&Ps[w][qt*16 + l][quad*8 + 32];
        }
#pragma unroll
        for (int dt = 0; dt < 4; ++dt) {
            half8 vb0 = *(half8*)&Vs[cur][dt*16 + l][quad*8];
            half8 vb1 = *(half8*)&Vs[cur][dt*16 + l][quad*8 + 32];
#pragma unroll
            for (int qt = 0; qt < 2; ++qt) {
                Of[qt][dt] = __builtin_amdgcn_mfma_f32_16x16x32_f16(pa[qt][0], vb0, Of[qt][dt], 0, 0, 0);
                Of[qt][dt] = __builtin_amdgcn_mfma_f32_16x16x32_f16(pa[qt][1], vb1, Of[qt][dt], 0, 0, 0);
            }
        }

        // commit prefetched chunk to the other buffer, single barrier
        if (kc < SEQ/BC - 1) {
            *(half8*)&Ks[1-cur][rs][cs] = kr;
            *(half8*)&Vs[1-cur][rs][cs] = vr;
        }
        __syncthreads();
    }

    // final l: reduce across quads, redistribute via per-wave LDS
#pragma unroll
    for (int qt = 0; qt < 2; ++qt) {
        lsum[qt] += __shfl_xor(lsum[qt], 16);
        lsum[qt] += __shfl_xor(lsum[qt], 32);
        if (quad == 0) Ls[w][qt*16 + l] = lsum[qt];
    }
    const int bt = bh >> 4, head = bh & 15;
    _Float16* opf = om + (size_t)(bt*SEQ + qc*256 + w*32)*DMODEL + head*DH;
#pragma unroll
    for (int qt = 0; qt < 2; ++qt) {
        float inv[4];
#pragma unroll
        for (int r = 0; r < 4; ++r) inv[r] = 1.0f / Ls[w][qt*16 + quad*4 + r];
#pragma unroll
        for (int dt = 0; dt < 4; ++dt)
#pragma unroll
            for (int r = 0; r < 4; ++r)
                opf[(size_t)(qt*16 + quad*4 + r)*DMODEL + dt*16 + l] =
                    (_Float16)(Of[qt][dt][r]*inv[r]);
    }
}

// ---------------------------------------------------------------------------
extern "C" void kernel_launch(void* const* d_in, const int* in_sizes, int n_in,
                              void* d_out, int out_size, void* d_ws, size_t ws_size,
                              hipStream_t stream)
{
    const float* x    = (const float*)d_in[0];
    const float* Wqkv = (const float*)d_in[1];
    const float* Wout = (const float*)d_in[2];
    const float* bout = (const float*)d_in[3];
    float* out = (float*)d_out;

    _Float16* ws   = (_Float16*)d_ws;
    _Float16* Xh   = ws;                  // 8388608
    _Float16* Wqkt = ws + 8388608;        // 3145728  [3072][1024]
    _Float16* Wot  = ws + 11534336;       // 1048576  [1024][1024]
    _Float16* qkvt = ws + 12582912;       // 25165824 [8192][3072]
    _Float16* qw   = ws + 37748736;       // 8388608
    _Float16* kw   = ws + 46137344;       // 8388608
    _Float16* vt   = ws + 54525952;       // 8388608  (end: 120 MiB)
    _Float16* om   = qkvt;                // alias: reused after rope_scatter

    hipLaunchKernelGGL(cvt_f16, dim3(4096), dim3(256), 0, stream,
                       x, Xh, 8388608);
    hipLaunchKernelGGL(tr_cvt, dim3(96, 32), dim3(256), 0, stream,
                       Wqkv, Wqkt, 1024, 3072);
    hipLaunchKernelGGL(tr_cvt, dim3(32, 32), dim3(256), 0, stream,
                       Wout, Wot, 1024, 1024);
    hipLaunchKernelGGL(gemm1_f16, dim3(12, 32), dim3(512), 0, stream,
                       Xh, Wqkt, qkvt, 8192, NQKV, DMODEL);
    hipLaunchKernelGGL(rope_scatter, dim3(16, 128), dim3(256), 0, stream,
                       qkvt, qw, kw, vt);
    hipLaunchKernelGGL(attn_mfma, dim3(4, 128), dim3(512), 0, stream,
                       qw, kw, vt, om);
    hipLaunchKernelGGL(gemm2_f16, dim3(8, 64), dim3(512), 0, stream,
                       om, Wot, bout, out, 8192, DMODEL, DMODEL);
}

// Round 10
// 241.227 us; speedup vs baseline: 1.0942x; 1.0251x over previous
//
#include <hip/hip_runtime.h>
#include <math.h>

#define DMODEL 1024
#define NQKV   3072
#define SEQ    1024
#define NH     16
#define DH     64
#define HS     (SEQ*DH)
constexpr float PI_F   = 3.14159265358979323846f;
constexpr float LOG2E  = 1.44269504088896f;

typedef _Float16 half8   __attribute__((ext_vector_type(8)));
typedef _Float16 half4   __attribute__((ext_vector_type(4)));
typedef float    floatx4 __attribute__((ext_vector_type(4)));

// async global->LDS, 16B per lane; LDS dest is wave-uniform base + lane*16
__device__ __forceinline__ void gload_lds16(const _Float16* g, _Float16* l) {
    __builtin_amdgcn_global_load_lds(
        (const __attribute__((address_space(1))) unsigned int*)g,
        (__attribute__((address_space(3)))       unsigned int*)l,
        16, 0, 0);
}

// ---------------------------------------------------------------------------
// flat fp32 -> f16 convert
// ---------------------------------------------------------------------------
__global__ __launch_bounds__(256) void cvt_f16(
    const float* __restrict__ in, _Float16* __restrict__ out, int n)
{
    int i = (blockIdx.x*256 + threadIdx.x)*8;
    if (i >= n) return;
    float4 a = *(const float4*)(in + i);
    float4 b = *(const float4*)(in + i + 4);
    half8 h;
    h[0]=(_Float16)a.x; h[1]=(_Float16)a.y; h[2]=(_Float16)a.z; h[3]=(_Float16)a.w;
    h[4]=(_Float16)b.x; h[5]=(_Float16)b.y; h[6]=(_Float16)b.z; h[7]=(_Float16)b.w;
    *(half8*)(out + i) = h;
}

// ---------------------------------------------------------------------------
// transpose + convert: in [R][C] fp32 -> out [C][R] f16   (32x32 tiles)
// ---------------------------------------------------------------------------
__global__ __launch_bounds__(256) void tr_cvt(
    const float* __restrict__ in, _Float16* __restrict__ out, int R, int C)
{
    __shared__ float T[32][33];
    const int bx = blockIdx.x, by = blockIdx.y;
    const int tx = threadIdx.x & 31, ty = threadIdx.x >> 5;
#pragma unroll
    for (int i = 0; i < 4; ++i)
        T[ty + i*8][tx] = in[(size_t)(by*32 + ty + i*8)*C + bx*32 + tx];
    __syncthreads();
#pragma unroll
    for (int i = 0; i < 4; ++i)
        out[(size_t)(bx*32 + ty + i*8)*R + by*32 + tx] = (_Float16)T[tx][ty + i*8];
}

// ---------------------------------------------------------------------------
// gemm1 v3: 128x128 tile, BK=64 as 2 k-halves, 8 waves (2Mx4N, 64x32/wave).
// LDS 64KB -> 2 blocks/CU = 4 waves/SIMD (was 256^2: 131KB, 1 block/CU =
// 2 waves/SIMD, Occupancy 14.5%). Same harness-verified gemm2-v2 skeleton:
// 1-gload stages, order/tile A0' B0' A1' B1'; SP0 gate vmcnt(3) retires
// {A0,B0}^t (last 2); SP1 gate vmcnt(3) retires {A1,B1}^t (last 0).
// Grid 24x64 = 1536 = 6x256 (zero tail, 1536%8=0 bijective XCD swizzle).
// ---------------------------------------------------------------------------
__global__ __launch_bounds__(512) void gemm1_f16(
    const _Float16* __restrict__ A, const _Float16* __restrict__ Bt,
    _Float16* __restrict__ C, int M, int N, int K)
{
    __shared__ _Float16 As[2][2][4096] __attribute__((aligned(16)));
    __shared__ _Float16 Bs[2][2][4096] __attribute__((aligned(16)));

    const int tid  = threadIdx.x;
    const int w    = tid >> 6, lane = tid & 63, quad = lane >> 4, l = lane & 15;
    const int wm   = (w >> 2)*64, wn = (w & 3)*32;

    int bid = blockIdx.y*gridDim.x + blockIdx.x;
    const int per = (gridDim.x*gridDim.y) >> 3;
    bid = (bid & 7)*per + (bid >> 3);
    const int bx = bid % gridDim.x, by = bid / gridDim.x;
    const int m0 = by*128, n0 = bx*128;

    const int rs   = tid >> 2;
    const int csrc = (tid & 3) ^ ((tid >> 3) & 3);
    const _Float16* ga = A  + (size_t)(m0 + rs)*K + csrc*8;
    const _Float16* gb = Bt + (size_t)(n0 + rs)*K + csrc*8;
    const int swz8 = (quad ^ ((l >> 1) & 3))*8;

    floatx4 acc[4][2];
#pragma unroll
    for (int i = 0; i < 4; ++i)
#pragma unroll
        for (int j = 0; j < 2; ++j)
#pragma unroll
            for (int r = 0; r < 4; ++r) acc[i][j][r] = 0.f;

    // prologue: tile 0, order A-k0, B-k0, A-k1, B-k1 (4 gloads/thread)
    gload_lds16(ga,      &As[0][0][w*512]);
    gload_lds16(gb,      &Bs[0][0][w*512]);
    gload_lds16(ga + 32, &As[0][1][w*512]);
    gload_lds16(gb + 32, &Bs[0][1][w*512]);

    const int KT = K / 64;
    for (int kt = 0; kt < KT; ++kt) {
        const int cur = kt & 1, nxt = cur ^ 1;
        const bool pf = (kt + 1 < KT);
        const size_t ko = (size_t)(kt + 1)*64;
        half8 af[4], bf[2];

        // ================= SP0 : k-half 0 =================
        if (pf) gload_lds16(ga + ko, &As[nxt][0][w*512]);
        if (pf) { asm volatile("s_waitcnt vmcnt(3)" ::: "memory"); }
        else    { asm volatile("s_waitcnt vmcnt(2)" ::: "memory"); }
        __builtin_amdgcn_s_barrier();
        __builtin_amdgcn_sched_barrier(0);
#pragma unroll
        for (int mt = 0; mt < 4; ++mt)
            af[mt] = *(half8*)&As[cur][0][(wm + mt*16 + l)*32 + swz8];
#pragma unroll
        for (int nt = 0; nt < 2; ++nt)
            bf[nt] = *(half8*)&Bs[cur][0][(wn + nt*16 + l)*32 + swz8];
        if (pf) gload_lds16(gb + ko, &Bs[nxt][0][w*512]);
        asm volatile("s_waitcnt lgkmcnt(0)" ::: "memory");
        __builtin_amdgcn_sched_barrier(0);
        __builtin_amdgcn_s_setprio(1);
#pragma unroll
        for (int mt = 0; mt < 4; ++mt)
#pragma unroll
            for (int nt = 0; nt < 2; ++nt)
                acc[mt][nt] = __builtin_amdgcn_mfma_f32_16x16x32_f16(af[mt], bf[nt], acc[mt][nt], 0, 0, 0);
        __builtin_amdgcn_s_setprio(0);

        // ================= SP1 : k-half 1 =================
        if (pf) gload_lds16(ga + ko + 32, &As[nxt][1][w*512]);
        if (pf) { asm volatile("s_waitcnt vmcnt(3)" ::: "memory"); }
        else    { asm volatile("s_waitcnt vmcnt(0)" ::: "memory"); }
        __builtin_amdgcn_s_barrier();
        __builtin_amdgcn_sched_barrier(0);
#pragma unroll
        for (int mt = 0; mt < 4; ++mt)
            af[mt] = *(half8*)&As[cur][1][(wm + mt*16 + l)*32 + swz8];
#pragma unroll
        for (int nt = 0; nt < 2; ++nt)
            bf[nt] = *(half8*)&Bs[cur][1][(wn + nt*16 + l)*32 + swz8];
        if (pf) gload_lds16(gb + ko + 32, &Bs[nxt][1][w*512]);
        asm volatile("s_waitcnt lgkmcnt(0)" ::: "memory");
        __builtin_amdgcn_sched_barrier(0);
        __builtin_amdgcn_s_setprio(1);
#pragma unroll
        for (int mt = 0; mt < 4; ++mt)
#pragma unroll
            for (int nt = 0; nt < 2; ++nt)
                acc[mt][nt] = __builtin_amdgcn_mfma_f32_16x16x32_f16(af[mt], bf[nt], acc[mt][nt], 0, 0, 0);
        __builtin_amdgcn_s_setprio(0);
    }

#pragma unroll
    for (int mt = 0; mt < 4; ++mt)
#pragma unroll
        for (int r = 0; r < 4; ++r) {
            size_t row = m0 + wm + mt*16 + quad*4 + r;
#pragma unroll
            for (int nt = 0; nt < 2; ++nt)
                C[row*N + n0 + wn + nt*16 + l] = (_Float16)acc[mt][nt][r];
        }
}

// ---------------------------------------------------------------------------
// gemm2 v2: 128x128 tile, same core, fp32 output + bias. Grid 8x64=512.
// ---------------------------------------------------------------------------
__global__ __launch_bounds__(512) void gemm2_f16(
    const _Float16* __restrict__ A, const _Float16* __restrict__ Bt,
    const float* __restrict__ bias, float* __restrict__ C, int M, int N, int K)
{
    __shared__ _Float16 As[2][2][4096] __attribute__((aligned(16)));
    __shared__ _Float16 Bs[2][2][4096] __attribute__((aligned(16)));

    const int tid  = threadIdx.x;
    const int w    = tid >> 6, lane = tid & 63, quad = lane >> 4, l = lane & 15;
    const int wm   = (w >> 2)*64, wn = (w & 3)*32;

    int bid = blockIdx.y*gridDim.x + blockIdx.x;
    const int per = (gridDim.x*gridDim.y) >> 3;
    bid = (bid & 7)*per + (bid >> 3);
    const int bx = bid % gridDim.x, by = bid / gridDim.x;
    const int m0 = by*128, n0 = bx*128;

    const int rs   = tid >> 2;
    const int csrc = (tid & 3) ^ ((tid >> 3) & 3);
    const _Float16* ga = A  + (size_t)(m0 + rs)*K + csrc*8;
    const _Float16* gb = Bt + (size_t)(n0 + rs)*K + csrc*8;
    const int swz8 = (quad ^ ((l >> 1) & 3))*8;

    floatx4 acc[4][2];
#pragma unroll
    for (int i = 0; i < 4; ++i)
#pragma unroll
        for (int j = 0; j < 2; ++j)
#pragma unroll
            for (int r = 0; r < 4; ++r) acc[i][j][r] = 0.f;

    gload_lds16(ga,      &As[0][0][w*512]);
    gload_lds16(gb,      &Bs[0][0][w*512]);
    gload_lds16(ga + 32, &As[0][1][w*512]);
    gload_lds16(gb + 32, &Bs[0][1][w*512]);

    const int KT = K / 64;
    for (int kt = 0; kt < KT; ++kt) {
        const int cur = kt & 1, nxt = cur ^ 1;
        const bool pf = (kt + 1 < KT);
        const size_t ko = (size_t)(kt + 1)*64;
        half8 af[4], bf[2];

        // ================= SP0 : k-half 0 =================
        if (pf) gload_lds16(ga + ko, &As[nxt][0][w*512]);
        if (pf) { asm volatile("s_waitcnt vmcnt(3)" ::: "memory"); }
        else    { asm volatile("s_waitcnt vmcnt(2)" ::: "memory"); }
        __builtin_amdgcn_s_barrier();
        __builtin_amdgcn_sched_barrier(0);
#pragma unroll
        for (int mt = 0; mt < 4; ++mt)
            af[mt] = *(half8*)&As[cur][0][(wm + mt*16 + l)*32 + swz8];
#pragma unroll
        for (int nt = 0; nt < 2; ++nt)
            bf[nt] = *(half8*)&Bs[cur][0][(wn + nt*16 + l)*32 + swz8];
        if (pf) gload_lds16(gb + ko, &Bs[nxt][0][w*512]);
        asm volatile("s_waitcnt lgkmcnt(0)" ::: "memory");
        __builtin_amdgcn_sched_barrier(0);
        __builtin_amdgcn_s_setprio(1);
#pragma unroll
        for (int mt = 0; mt < 4; ++mt)
#pragma unroll
            for (int nt = 0; nt < 2; ++nt)
                acc[mt][nt] = __builtin_amdgcn_mfma_f32_16x16x32_f16(af[mt], bf[nt], acc[mt][nt], 0, 0, 0);
        __builtin_amdgcn_s_setprio(0);

        // ================= SP1 : k-half 1 =================
        if (pf) gload_lds16(ga + ko + 32, &As[nxt][1][w*512]);
        if (pf) { asm volatile("s_waitcnt vmcnt(3)" ::: "memory"); }
        else    { asm volatile("s_waitcnt vmcnt(0)" ::: "memory"); }
        __builtin_amdgcn_s_barrier();
        __builtin_amdgcn_sched_barrier(0);
#pragma unroll
        for (int mt = 0; mt < 4; ++mt)
            af[mt] = *(half8*)&As[cur][1][(wm + mt*16 + l)*32 + swz8];
#pragma unroll
        for (int nt = 0; nt < 2; ++nt)
            bf[nt] = *(half8*)&Bs[cur][1][(wn + nt*16 + l)*32 + swz8];
        if (pf) gload_lds16(gb + ko + 32, &Bs[nxt][1][w*512]);
        asm volatile("s_waitcnt lgkmcnt(0)" ::: "memory");
        __builtin_amdgcn_sched_barrier(0);
        __builtin_amdgcn_s_setprio(1);
#pragma unroll
        for (int mt = 0; mt < 4; ++mt)
#pragma unroll
            for (int nt = 0; nt < 2; ++nt)
                acc[mt][nt] = __builtin_amdgcn_mfma_f32_16x16x32_f16(af[mt], bf[nt], acc[mt][nt], 0, 0, 0);
        __builtin_amdgcn_s_setprio(0);
    }

#pragma unroll
    for (int mt = 0; mt < 4; ++mt)
#pragma unroll
        for (int r = 0; r < 4; ++r) {
            size_t row = m0 + wm + mt*16 + quad*4 + r;
#pragma unroll
            for (int nt = 0; nt < 2; ++nt) {
                int col = n0 + wn + nt*16 + l;
                C[row*N + col] = acc[mt][nt][r] + bias[col];
            }
        }
}

// ---------------------------------------------------------------------------
// rope + scatter. q pre-scaled by (1/8)*log2e so attention exp is bare exp2.
// ---------------------------------------------------------------------------
__global__ __launch_bounds__(256) void rope_scatter(
    const _Float16* __restrict__ qkv,
    _Float16* __restrict__ qw, _Float16* __restrict__ kw,
    _Float16* __restrict__ vt)
{
    const int sc = blockIdx.x;
    const int bh = blockIdx.y;
    const int bt = bh >> 4, head = bh & 15;
    const int s0 = sc*64;
    const int tid = threadIdx.x;
    const int d0 = (tid & 7)*8;

    __shared__ _Float16 T[64][80];

#pragma unroll
    for (int half = 0; half < 2; ++half) {
        const int r = (tid >> 3) + half*32;
        const int s = s0 + r;
        const _Float16* src = qkv + (size_t)(bt*SEQ + s)*NQKV + head*DH + d0;
        half8 hq = *(const half8*)(src);
        half8 hk = *(const half8*)(src + DMODEL);
        half8 hv = *(const half8*)(src + 2*DMODEL);
        float fq[8], fk[8];
#pragma unroll
        for (int j = 0; j < 8; ++j) { fq[j] = (float)hq[j]; fk[j] = (float)hk[j]; }
        const int hp = s >> 5, wp = s & 31;
        const float ph = -1.0f + hp*(2.0f/31.0f);
        const float pw = -1.0f + wp*(2.0f/31.0f);
#pragma unroll
        for (int p = 0; p < 4; ++p) {
            int pg = (d0 >> 1) + p;
            float pos = (pg < 16) ? ph : pw;
            int   gi  = (pg < 16) ? pg : (pg - 16);
            float th  = pos * ((1.0f + gi*(127.0f/15.0f)) * PI_F);
            float sn, cs;
            sincosf(th, &sn, &cs);
            float q1 = fq[2*p], q2 = fq[2*p+1];
            fq[2*p]   = q1*cs - q2*sn;
            fq[2*p+1] = q2*cs + q1*sn;
            float k1 = fk[2*p], k2 = fk[2*p+1];
            fk[2*p]   = k1*cs - k2*sn;
            fk[2*p+1] = k2*cs + k1*sn;
        }
        half8 oq, ok;
        const float qsc = 0.125f * LOG2E;
#pragma unroll
        for (int j = 0; j < 8; ++j) {
            oq[j] = (_Float16)(fq[j]*qsc);
            ok[j] = (_Float16)fk[j];
        }
        *(half8*)(qw + (size_t)bh*HS + (size_t)s*DH + d0) = oq;
        *(half8*)(kw + (size_t)bh*HS + (size_t)s*DH + d0) = ok;
#pragma unroll
        for (int j = 0; j < 8; ++j) T[d0 + j][r] = hv[j];
    }
    __syncthreads();
    const int d = tid >> 2, so = (tid & 3)*16;
    half8 v0 = *(half8*)&T[d][so];
    half8 v1 = *(half8*)&T[d][so + 8];
    _Float16* dst = vt + (size_t)bh*HS + (size_t)d*SEQ + s0 + so;
    *(half8*)dst       = v0;
    *(half8*)(dst + 8) = v1;
}

// ---------------------------------------------------------------------------
// Flash attention v6: BQ=256 per block, 8 waves x 32 queries (2 q-tiles).
// 8 waves share each K/V chunk; LDS 70.6KB -> 2 blocks/CU = 4 waves/SIMD
// (R8-measured win). Plain launch_bounds(512): no VGPR cap (R9's (512,4)
// pin suspected spill-regression).
// ---------------------------------------------------------------------------
#define BC  64
#define LDH 68     // padded row stride (halfwords): rows shift 2 banks; <=2-way on frags

__global__ __launch_bounds__(512) void attn_mfma(
    const _Float16* __restrict__ qw, const _Float16* __restrict__ kw,
    const _Float16* __restrict__ vt, _Float16* __restrict__ om)
{
    const int qc = blockIdx.x;    // 0..3  (256-query chunk)
    const int bh = blockIdx.y;    // 0..127
    const int tid  = threadIdx.x;
    const int w    = tid >> 6;    // 0..7
    const int lane = tid & 63;
    const int quad = lane >> 4;
    const int l    = lane & 15;

    __shared__ _Float16 Ks[2][BC][LDH];
    __shared__ _Float16 Vs[2][DH][LDH];
    __shared__ _Float16 Ps[8][32][LDH];
    __shared__ float    Ls[8][32];

    const _Float16* qp = qw + (size_t)bh*HS + (size_t)(qc*256 + w*32)*DH;
    const _Float16* kp = kw + (size_t)bh*HS;
    const _Float16* vp = vt + (size_t)bh*HS;   // [d][1024]

    // Q B-frags for this wave's 2 q-tiles (held all loop)
    half8 qf[2][2];
#pragma unroll
    for (int qt = 0; qt < 2; ++qt) {
        qf[qt][0] = *(const half8*)(qp + (size_t)(qt*16 + l)*DH + quad*8);
        qf[qt][1] = *(const half8*)(qp + (size_t)(qt*16 + l)*DH + quad*8 + 32);
    }

    // staging: 512 threads cover 64 rows x 8 col-chunks, 1 K + 1 V load each
    const int rs = tid >> 3;           // 0..63
    const int cs = (tid & 7)*8;        // 0..56

    half8 kr = *(const half8*)(kp + (size_t)rs*DH + cs);
    half8 vr = *(const half8*)(vp + (size_t)rs*SEQ + cs);
    *(half8*)&Ks[0][rs][cs] = kr;
    *(half8*)&Vs[0][rs][cs] = vr;

    floatx4 Of[2][4];
#pragma unroll
    for (int qt = 0; qt < 2; ++qt)
#pragma unroll
        for (int dt = 0; dt < 4; ++dt)
#pragma unroll
            for (int r = 0; r < 4; ++r) Of[qt][dt][r] = 0.f;
    float lsum[2] = {0.f, 0.f};

    __syncthreads();

    for (int kc = 0; kc < SEQ/BC; ++kc) {
        const int cur = kc & 1;
        // prefetch chunk kc+1 into registers (hides under compute)
        if (kc < SEQ/BC - 1) {
            const _Float16* kn = kp + (size_t)(kc+1)*BC*DH;
            const _Float16* vn = vp + (size_t)(kc+1)*BC;
            kr = *(const half8*)(kn + (size_t)rs*DH + cs);
            vr = *(const half8*)(vn + (size_t)rs*SEQ + cs);
        }

        // S^T = K.Q^T, fused exp2 + P store per (kg, qt); one S tile live
#pragma unroll
        for (int kg = 0; kg < 4; ++kg) {
            half8 af0 = *(half8*)&Ks[cur][kg*16 + l][quad*8];
            half8 af1 = *(half8*)&Ks[cur][kg*16 + l][quad*8 + 32];
#pragma unroll
            for (int qt = 0; qt < 2; ++qt) {
                floatx4 a;
#pragma unroll
                for (int r = 0; r < 4; ++r) a[r] = 0.f;
                a = __builtin_amdgcn_mfma_f32_16x16x32_f16(af0, qf[qt][0], a, 0, 0, 0);
                a = __builtin_amdgcn_mfma_f32_16x16x32_f16(af1, qf[qt][1], a, 0, 0, 0);
                half4 p4;
#pragma unroll
                for (int r = 0; r < 4; ++r) {
                    float p = __builtin_amdgcn_exp2f(a[r]);
                    lsum[qt] += p;
                    p4[r] = (_Float16)p;
                }
                *(half4*)&Ps[w][qt*16 + l][kg*16 + quad*4] = p4;
            }
        }
        // PV: A = P b128 frags (wave-private), B = V^T (read once, 2x reuse)
        half8 pa[2][2];
#pragma unroll
        for (int qt = 0; qt < 2; ++qt) {
            pa[qt][0] = *(half8*)&Ps[w][qt*16 + l][quad*8];
            pa[qt][1] = *(half8*)&Ps[w][qt*16 + l][quad*8 + 32];
        }
#pragma unroll
        for (int dt = 0; dt < 4; ++dt) {
            half8 vb0 = *(half8*)&Vs[cur][dt*16 + l][quad*8];
            half8 vb1 = *(half8*)&Vs[cur][dt*16 + l][quad*8 + 32];
#pragma unroll
            for (int qt = 0; qt < 2; ++qt) {
                Of[qt][dt] = __builtin_amdgcn_mfma_f32_16x16x32_f16(pa[qt][0], vb0, Of[qt][dt], 0, 0, 0);
                Of[qt][dt] = __builtin_amdgcn_mfma_f32_16x16x32_f16(pa[qt][1], vb1, Of[qt][dt], 0, 0, 0);
            }
        }

        // commit prefetched chunk to the other buffer, single barrier
        if (kc < SEQ/BC - 1) {
            *(half8*)&Ks[1-cur][rs][cs] = kr;
            *(half8*)&Vs[1-cur][rs][cs] = vr;
        }
        __syncthreads();
    }

    // final l: reduce across quads, redistribute via per-wave LDS
#pragma unroll
    for (int qt = 0; qt < 2; ++qt) {
        lsum[qt] += __shfl_xor(lsum[qt], 16);
        lsum[qt] += __shfl_xor(lsum[qt], 32);
        if (quad == 0) Ls[w][qt*16 + l] = lsum[qt];
    }
    const int bt = bh >> 4, head = bh & 15;
    _Float16* opf = om + (size_t)(bt*SEQ + qc*256 + w*32)*DMODEL + head*DH;
#pragma unroll
    for (int qt = 0; qt < 2; ++qt) {
        float inv[4];
#pragma unroll
        for (int r = 0; r < 4; ++r) inv[r] = 1.0f / Ls[w][qt*16 + quad*4 + r];
#pragma unroll
        for (int dt = 0; dt < 4; ++dt)
#pragma unroll
            for (int r = 0; r < 4; ++r)
                opf[(size_t)(qt*16 + quad*4 + r)*DMODEL + dt*16 + l] =
                    (_Float16)(Of[qt][dt][r]*inv[r]);
    }
}

// ---------------------------------------------------------------------------
extern "C" void kernel_launch(void* const* d_in, const int* in_sizes, int n_in,
                              void* d_out, int out_size, void* d_ws, size_t ws_size,
                              hipStream_t stream)
{
    const float* x    = (const float*)d_in[0];
    const float* Wqkv = (const float*)d_in[1];
    const float* Wout = (const float*)d_in[2];
    const float* bout = (const float*)d_in[3];
    float* out = (float*)d_out;

    _Float16* ws   = (_Float16*)d_ws;
    _Float16* Xh   = ws;                  // 8388608
    _Float16* Wqkt = ws + 8388608;        // 3145728  [3072][1024]
    _Float16* Wot  = ws + 11534336;       // 1048576  [1024][1024]
    _Float16* qkvt = ws + 12582912;       // 25165824 [8192][3072]
    _Float16* qw   = ws + 37748736;       // 8388608
    _Float16* kw   = ws + 46137344;       // 8388608
    _Float16* vt   = ws + 54525952;       // 8388608  (end: 120 MiB)
    _Float16* om   = qkvt;                // alias: reused after rope_scatter

    hipLaunchKernelGGL(cvt_f16, dim3(4096), dim3(256), 0, stream,
                       x, Xh, 8388608);
    hipLaunchKernelGGL(tr_cvt, dim3(96, 32), dim3(256), 0, stream,
                       Wqkv, Wqkt, 1024, 3072);
    hipLaunchKernelGGL(tr_cvt, dim3(32, 32), dim3(256), 0, stream,
                       Wout, Wot, 1024, 1024);
    hipLaunchKernelGGL(gemm1_f16, dim3(24, 64), dim3(512), 0, stream,
                       Xh, Wqkt, qkvt, 8192, NQKV, DMODEL);
    hipLaunchKernelGGL(rope_scatter, dim3(16, 128), dim3(256), 0, stream,
                       qkvt, qw, kw, vt);
    hipLaunchKernelGGL(attn_mfma, dim3(4, 128), dim3(512), 0, stream,
                       qw, kw, vt, om);
    hipLaunchKernelGGL(gemm2_f16, dim3(8, 64), dim3(512), 0, stream,
                       om, Wot, bout, out, 8192, DMODEL, DMODEL);
}